// Round 8
// baseline (213.533 us; speedup 1.0000x reference)
//
#include <hip/hip_runtime.h>
#include <hip/hip_bf16.h>

typedef __bf16 bf16x8 __attribute__((ext_vector_type(8)));
typedef __bf16 bf16x4 __attribute__((ext_vector_type(4)));
typedef float floatx4 __attribute__((ext_vector_type(4)));

#define MFMA16(a, b, c) __builtin_amdgcn_mfma_f32_16x16x32_bf16(a, b, c, 0, 0, 0)
#define AS1 __attribute__((address_space(1)))
#define AS3 __attribute__((address_space(3)))

constexpr int D = 1024;
constexpr int L = 2048;
constexpr int BB = 2;
constexpr int DH = 64;
constexpr float NEG_BIG = -1e30f;                 // exp2 -> 0, fast-math safe
constexpr float SCALE_LOG2E = 0.125f * 1.4426950408889634f;  // folded into Q projection

// async global->LDS, 16B per lane (dest = wave-uniform base + lane*16)
__device__ __forceinline__ void gld16(const __bf16* g, __bf16* l) {
  __builtin_amdgcn_global_load_lds((AS1 void*)g, (AS3 void*)l, 16, 0, 0);
}

// ---------------------------------------------------------------------------
// Convert fp32 x (q,k,v inputs) -> canonical bf16 [3][4096][1024]
// ---------------------------------------------------------------------------
__global__ __launch_bounds__(256) void cvt_x(const float* __restrict__ xq, const float* __restrict__ xk,
                                             const float* __restrict__ xv, __bf16* __restrict__ out) {
  const int z = blockIdx.z;
  const float* src = z == 0 ? xq : z == 1 ? xk : xv;
  __bf16* dst = out + (size_t)z * BB * L * D;
  const int N = BB * L * D;
  const int stride = gridDim.x * 256 * 4;
  for (int i = (blockIdx.x * 256 + threadIdx.x) * 4; i < N; i += stride) {
    float4 f = *(const float4*)&src[i];
    bf16x4 b = {(__bf16)f.x, (__bf16)f.y, (__bf16)f.z, (__bf16)f.w};
    *(bf16x4*)&dst[i] = b;
  }
}

// ---------------------------------------------------------------------------
// Transpose 4 fp32 weight matrices W[K][N] -> canonical bf16 Wt[N][K]
// ---------------------------------------------------------------------------
__global__ void transpose_w(const float* __restrict__ w0, const float* __restrict__ w1,
                            const float* __restrict__ w2, const float* __restrict__ w3,
                            __bf16* __restrict__ out) {
  __shared__ __bf16 tile[32][33];
  int mat = blockIdx.z;
  const float* src = mat == 0 ? w0 : mat == 1 ? w1 : mat == 2 ? w2 : w3;
  __bf16* dst = out + (size_t)mat * D * D;
  int bx = blockIdx.x * 32, by = blockIdx.y * 32;
  int tx = threadIdx.x, ty = threadIdx.y;  // block (32, 8)
#pragma unroll
  for (int i = 0; i < 32; i += 8)
    tile[ty + i][tx] = (__bf16)src[(size_t)(by + ty + i) * D + bx + tx];
  __syncthreads();
#pragma unroll
  for (int i = 0; i < 32; i += 8)
    dst[(size_t)(bx + ty + i) * D + by + tx] = tile[tx][ty + i];
}

// ---------------------------------------------------------------------------
// GEMM main loop: T4 counted-vmcnt 2-phase pipeline (frozen from R5).
// 128x128 tile, BK=32, double-buffered LDS in sm[0..16383].
// LDS swizzle (both-sides, rule 21): 2-row-granular XOR, 2-way = free.
// ---------------------------------------------------------------------------
__device__ __forceinline__ void stage32(const __bf16* __restrict__ A, const __bf16* __restrict__ Bt,
                                        __bf16* sA, __bf16* sB, int m0, int n0, int kb,
                                        int r, int sc, int dst) {
  // thread t: r = t>>2 (0..63), sc = ((t&3) ^ ((r>>1)&3))*8, dst = t*8
  gld16(&A[(size_t)(m0 + r) * 1024 + kb + sc],       &sA[dst]);
  gld16(&A[(size_t)(m0 + 64 + r) * 1024 + kb + sc],  &sA[2048 + dst]);  // (64+r)>>1 &3 == (r>>1)&3
  gld16(&Bt[(size_t)(n0 + r) * 1024 + kb + sc],      &sB[dst]);
  gld16(&Bt[(size_t)(n0 + 64 + r) * 1024 + kb + sc], &sB[2048 + dst]);
}

__device__ __forceinline__ void gemm_core(const __bf16* __restrict__ A, const __bf16* __restrict__ Bt,
                                          __bf16* sm, int m0, int n0, int wm, int wn,
                                          int l15, int quad, int t, floatx4 (&acc)[4][4]) {
  const int r = t >> 2;                         // 0..63
  const int sc = ((t & 3) ^ ((r >> 1) & 3)) * 8;
  const int dst = t * 8;
  const int sw2 = (l15 >> 1) & 3;               // (row>>1)&3 for all frag rows

  // prologue: stage K-step 0 into buffer 0
  stage32(A, Bt, sm, sm + 8192, m0, n0, 0, r, sc, dst);

  int cur = 0;
  for (int kb = 0; kb < 1024; kb += 32) {
    if (kb + 32 < 1024) {
      stage32(A, Bt, sm + (cur ^ 1) * 4096, sm + 8192 + (cur ^ 1) * 4096, m0, n0, kb + 32, r, sc, dst);
      asm volatile("s_waitcnt vmcnt(4)" ::: "memory");   // tile kb landed; kb+32 stays in flight
    } else {
      asm volatile("s_waitcnt vmcnt(0)" ::: "memory");   // last tile
    }
    __builtin_amdgcn_s_barrier();                        // all waves: tile kb resident

    const __bf16* sAc = sm + cur * 4096;
    const __bf16* sBc = sm + 8192 + cur * 4096;
    bf16x8 af[4], bf_[4];
#pragma unroll
    for (int i = 0; i < 4; i++) {
      const int row = wm * 64 + i * 16 + l15;
      af[i] = *(const bf16x8*)&sAc[(row * 4 + (quad ^ sw2)) * 8];
    }
#pragma unroll
    for (int j = 0; j < 4; j++) {
      const int row = wn * 64 + j * 16 + l15;
      bf_[j] = *(const bf16x8*)&sBc[(row * 4 + (quad ^ sw2)) * 8];
    }
    asm volatile("s_waitcnt lgkmcnt(0)" ::: "memory");   // my reads retired
    __builtin_amdgcn_sched_barrier(0);                   // rule 18: no MFMA hoist
    __builtin_amdgcn_s_barrier();                        // all reads retired -> overwrite ok

#pragma unroll
    for (int i = 0; i < 4; i++)
#pragma unroll
      for (int j = 0; j < 4; j++)
        acc[i][j] = MFMA16(af[i], bf_[j], acc[i][j]);    // overlaps next stage issue

    cur ^= 1;
  }
}

// ---------------------------------------------------------------------------
// QKV projection. z=0: Q scaled, [bh][l][dh]. z=1: K, [bh][l][dh].
// z=2: V TRANSPOSED [bh][dh][L]. XCD-swizzled (FETCH 101.5 -> 22.7 MB, R2).
// Epilogue: LDS-repack + coalesced 16B stores (R6 win: total 228.6 -> 206.1).
// ---------------------------------------------------------------------------
__global__ __launch_bounds__(256, 3) void gemm_proj(const __bf16* __restrict__ xc, const __bf16* __restrict__ wt,
                                                    const float* __restrict__ bq, const float* __restrict__ bk,
                                                    const float* __restrict__ bv, __bf16* __restrict__ qkv) {
  __shared__ __align__(16) __bf16 smem[17408];  // K-loop: 16384; epilogue T: 128x136

  const int flat = (blockIdx.z * 32 + blockIdx.y) * 8 + blockIdx.x;
  const int s = (flat & 7) * 96 + (flat >> 3);
  const int z = s >> 8;           // s / 256
  const int rem = s & 255;
  const int by = rem >> 3, bx = rem & 7;

  const __bf16* A = xc + (size_t)z * BB * L * D;
  const __bf16* Bt = wt + (size_t)z * D * D;
  const float* bias = z == 0 ? bq : z == 1 ? bk : bv;
  __bf16* dst = qkv + (size_t)z * BB * L * D;

  const int t = threadIdx.x;
  const int lane = t & 63;
  const int w = t >> 6;
  const int wm = w >> 1, wn = w & 1;
  const int l15 = lane & 15, quad = lane >> 4;
  const int m0 = by * 128, n0 = bx * 128;

  floatx4 acc[4][4];
#pragma unroll
  for (int i = 0; i < 4; i++)
#pragma unroll
    for (int j = 0; j < 4; j++) acc[i][j] = (floatx4){0.f, 0.f, 0.f, 0.f};

  gemm_core(A, Bt, smem, m0, n0, wm, wn, l15, quad, t, acc);

  float bvv[4];
#pragma unroll
  for (int j = 0; j < 4; j++) bvv[j] = bias[n0 + wn * 64 + j * 16 + l15];

  // ---- phase 1: C-tile -> LDS (K-loop buffers dead after final barrier) ----
  constexpr int TP = 136;                       // pad: row stride 272 B spreads banks
  __bf16* T = smem;
  if (z < 2) {
#pragma unroll
    for (int i = 0; i < 4; i++) {
      const int mrowb = wm * 64 + i * 16 + quad * 4;
#pragma unroll
      for (int j = 0; j < 4; j++) {
        const int ccol = wn * 64 + j * 16 + l15;
#pragma unroll
        for (int rr = 0; rr < 4; rr++) {
          float val = acc[i][j][rr] + bvv[j];
          if (z == 0) val *= SCALE_LOG2E;
          T[(mrowb + rr) * TP + ccol] = (__bf16)val;
        }
      }
    }
  } else {
#pragma unroll
    for (int i = 0; i < 4; i++) {
      const int mrowb = wm * 64 + i * 16 + quad * 4;
#pragma unroll
      for (int j = 0; j < 4; j++) {
        const int ccol = wn * 64 + j * 16 + l15;
        bf16x4 v4;
#pragma unroll
        for (int rr = 0; rr < 4; rr++) v4[rr] = (__bf16)(acc[i][j][rr] + bvv[j]);
        *(bf16x4*)&T[ccol * TP + mrowb] = v4;
      }
    }
  }
  __syncthreads();

  // ---- phase 2: coalesced 16B stores (2048 chunks, 8 per thread) ----
  const int b = m0 >> 11;                       // tile never crosses batch boundary
  const int l0 = m0 & 2047;
  if (z < 2) {
#pragma unroll
    for (int sH = 0; sH < 8; sH++) {
      const int c = sH * 256 + t;
      const int mrow = c >> 4, k16 = c & 15;
      const int h = (n0 >> 6) + (k16 >> 3);
      const int d0 = (k16 & 7) * 8;
      bf16x8 v = *(const bf16x8*)&T[mrow * TP + k16 * 8];
      *(bf16x8*)&dst[((size_t)(b * 16 + h) * 2048 + l0 + mrow) * 64 + d0] = v;
    }
  } else {
    const int R0 = (b * 16 + (n0 >> 6)) * 64;   // V^T rows for this col-panel are contiguous
#pragma unroll
    for (int sH = 0; sH < 8; sH++) {
      const int c = sH * 256 + t;
      const int ccol = c >> 4, k16 = c & 15;
      bf16x8 v = *(const bf16x8*)&T[ccol * TP + k16 * 8];
      *(bf16x8*)&dst[(size_t)(R0 + ccol) * 2048 + l0 + k16 * 8] = v;
    }
  }
}

// ---------------------------------------------------------------------------
// Output projection: ctx bf16 [4096][1024] @ Wo^T + bo -> fp32 out
// ---------------------------------------------------------------------------
__global__ __launch_bounds__(256, 3) void gemm_o(const __bf16* __restrict__ ctx, const __bf16* __restrict__ wto,
                                                 const float* __restrict__ bo, float* __restrict__ out) {
  __shared__ __align__(16) __bf16 smem[16384];

  const int flat = blockIdx.y * 8 + blockIdx.x;      // grid (8,32) = 256 blocks
  const int s = (flat & 7) * 32 + (flat >> 3);
  const int by = s >> 3, bx = s & 7;

  const int t = threadIdx.x;
  const int lane = t & 63;
  const int w = t >> 6;
  const int wm = w >> 1, wn = w & 1;
  const int l15 = lane & 15, quad = lane >> 4;
  const int m0 = by * 128, n0 = bx * 128;

  floatx4 acc[4][4];
#pragma unroll
  for (int i = 0; i < 4; i++)
#pragma unroll
    for (int j = 0; j < 4; j++) acc[i][j] = (floatx4){0.f, 0.f, 0.f, 0.f};

  gemm_core(ctx, wto, smem, m0, n0, wm, wn, l15, quad, t, acc);

  float bvv[4];
#pragma unroll
  for (int j = 0; j < 4; j++) bvv[j] = bo[n0 + wn * 64 + j * 16 + l15];

#pragma unroll
  for (int i = 0; i < 4; i++) {
    const int rowb = m0 + wm * 64 + i * 16 + quad * 4;
#pragma unroll
    for (int j = 0; j < 4; j++) {
      const int col = n0 + wn * 64 + j * 16 + l15;
#pragma unroll
      for (int rr = 0; rr < 4; rr++)
        out[(size_t)(rowb + rr) * 1024 + col] = acc[i][j][rr] + bvv[j];
    }
  }
}

// ---------------------------------------------------------------------------
// Flash attention, causal. q,k in [bh][L][64]; vT in [bh][64][L] (all bf16).
// Q pre-scaled by 0.125*log2e; no max subtraction (|S2|<~9 bounded), row sums
// deferred -> k-tile order is irrelevant (pure accumulation).
//
// R8 rebuild around the measured bottleneck (R6/R7: time = max-iters x
// 1.42us/iter; __syncthreads drained the same-iter prefetch -> ~3400cyc
// serial latency chain per iter):
//  1. T4 counted-vmcnt (gemm_core's proven pattern): stage(it+1), vmcnt(4)
//     waits only tile it (issued a FULL iter ago), raw barriers, lgkmcnt(0)
//     +sched_barrier before the second barrier. Prefetch never drains mid-loop.
//  2. Shared-KV q-tile pairing: block p owns q-tiles A=31-p (long) and B=p
//     (short); ONE kt sweep 0..31-p updates A always, B while kt<=p.
//     -> uniform 33 q-tile-updates/block, each staged tile serves 2 q-tiles,
//     all blocks sweep kt from 0 near-synced (R6-grade L2 reuse; fixes R7's
//     FETCH 62->119 MB regression).
// Grid (16,32) = 512 blocks = 2/CU; launch_bounds(256,2) for VGPR headroom
// (dual accumulators ~+48 VGPR).
// ---------------------------------------------------------------------------
__global__ __launch_bounds__(256, 2) void flash_attn(const __bf16* __restrict__ q, const __bf16* __restrict__ k,
                                                     const __bf16* __restrict__ vT, __bf16* __restrict__ ctx) {
  __shared__ __align__(16) __bf16 kbuf[2][4096];  // K tile: 64 rows x 64 d, swizzled
  __shared__ __align__(16) __bf16 vbuf[2][4096];  // V^T tile: 64 d x 64 kpos, swizzled

  const int t = threadIdx.x;
  const int lane = t & 63;
  const int w = t >> 6;                 // wave 0..3
  const int l15 = lane & 15, quad = lane >> 4;
  const int bh = blockIdx.y;
  const int p = (blockIdx.x + blockIdx.y) & 15;    // pair index, diag-swizzled
  const int qtA = 31 - p;               // long q-tile; also the last k-tile
  const int qtB = p;                    // short q-tile

  const __bf16* qb = q + (size_t)bh * L * DH;
  const __bf16* kb_ = k + (size_t)bh * L * DH;
  const __bf16* vb = vT + (size_t)bh * DH * L;

  // staging map: thread t covers LDS chunks c0 = t, c1 = 256+t (16B each).
  // chunk c holds row r = c>>3, swizzled sub-chunk (c&7) -> col8 = (c&7)^(r&7)
  const int c0 = t, c1 = 256 + t;
  const int kr0 = c0 >> 3, kd0 = ((c0 & 7) ^ (kr0 & 7)) * 8;
  const int kr1 = c1 >> 3, kd1 = ((c1 & 7) ^ (kr1 & 7)) * 8;

  const int qrA = qtA * 64 + w * 16 + l15;         // this lane's q row, tile A
  const int qrB = qtB * 64 + w * 16 + l15;         // and tile B
  const bf16x8 aqA0 = *(const bf16x8*)&qb[(size_t)qrA * 64 + quad * 8];
  const bf16x8 aqA1 = *(const bf16x8*)&qb[(size_t)qrA * 64 + 32 + quad * 8];
  const bf16x8 aqB0 = *(const bf16x8*)&qb[(size_t)qrB * 64 + quad * 8];
  const bf16x8 aqB1 = *(const bf16x8*)&qb[(size_t)qrB * 64 + 32 + quad * 8];

  floatx4 oA[4], oB[4];
#pragma unroll
  for (int nt = 0; nt < 4; nt++) {
    oA[nt] = (floatx4){0.f, 0.f, 0.f, 0.f};
    oB[nt] = (floatx4){0.f, 0.f, 0.f, 0.f};
  }
  float psA = 0.f, psB = 0.f;

  // preload k-tile 0 into buf 0 (stays in flight; first iter's vmcnt waits it)
  gld16(&kb_[(size_t)kr0 * 64 + kd0], &kbuf[0][c0 * 8]);
  gld16(&kb_[(size_t)kr1 * 64 + kd1], &kbuf[0][c1 * 8]);
  gld16(&vb[(size_t)kr0 * L + kd0],   &vbuf[0][c0 * 8]);
  gld16(&vb[(size_t)kr1 * L + kd1],   &vbuf[0][c1 * 8]);

#pragma unroll 1
  for (int it = 0; it <= qtA; ++it) {
    const int cur = it & 1;
    const int kt = it * 64;

    // ---- stage k-tile it+1; wait ONLY tile it (counted vmcnt, T4) ----
    if (it < qtA) {
      const int ktn = kt + 64;
      gld16(&kb_[(size_t)(ktn + kr0) * 64 + kd0], &kbuf[cur ^ 1][c0 * 8]);
      gld16(&kb_[(size_t)(ktn + kr1) * 64 + kd1], &kbuf[cur ^ 1][c1 * 8]);
      gld16(&vb[(size_t)kr0 * L + ktn + kd0],     &vbuf[cur ^ 1][c0 * 8]);
      gld16(&vb[(size_t)kr1 * L + ktn + kd1],     &vbuf[cur ^ 1][c1 * 8]);
      asm volatile("s_waitcnt vmcnt(4)" ::: "memory");   // tile it landed; it+1 in flight
    } else {
      asm volatile("s_waitcnt vmcnt(0)" ::: "memory");   // last tile
    }
    __builtin_amdgcn_s_barrier();                        // all waves: tile it resident

    const bool diagA = (it == qtA);
    const bool doB   = (it <= qtB);
    const bool diagB = (it == qtB);

#pragma unroll
    for (int sp = 0; sp < 2; ++sp) {      // two 32-wide kpos windows
      // ---- K fragments (shared by both q-tiles) ----
      bf16x8 kf0[2], kf1[2];
#pragma unroll
      for (int u = 0; u < 2; ++u) {
        const int kr = (2 * sp + u) * 16 + l15;
        kf0[u] = *(const bf16x8*)&kbuf[cur][(kr * 8 + (quad ^ (kr & 7))) * 8];
        kf1[u] = *(const bf16x8*)&kbuf[cur][(kr * 8 + ((quad + 4) ^ (kr & 7))) * 8];
      }

      // ---- S^T = K Q^T, mask, P = exp2: tile A ----
      bf16x8 paA;
#pragma unroll
      for (int u = 0; u < 2; ++u) {
        floatx4 zz = (floatx4){0.f, 0.f, 0.f, 0.f};
        zz = MFMA16(kf0[u], aqA0, zz);
        zz = MFMA16(kf1[u], aqA1, zz);
        if (diagA) {
          const int kgb = kt + (2 * sp + u) * 16 + quad * 4;
#pragma unroll
          for (int rr = 0; rr < 4; rr++)
            if (kgb + rr > qrA) zz[rr] = NEG_BIG;
        }
#pragma unroll
        for (int rr = 0; rr < 4; rr++) {
          const float pv = __builtin_amdgcn_exp2f(zz[rr]);
          psA += pv;
          paA[u * 4 + rr] = (__bf16)pv;
        }
      }

      // ---- tile B (only while kt <= qtB; block-uniform branch) ----
      bf16x8 paB;
      if (doB) {
#pragma unroll
        for (int u = 0; u < 2; ++u) {
          floatx4 zz = (floatx4){0.f, 0.f, 0.f, 0.f};
          zz = MFMA16(kf0[u], aqB0, zz);
          zz = MFMA16(kf1[u], aqB1, zz);
          if (diagB) {
            const int kgb = kt + (2 * sp + u) * 16 + quad * 4;
#pragma unroll
            for (int rr = 0; rr < 4; rr++)
              if (kgb + rr > qrB) zz[rr] = NEG_BIG;
          }
#pragma unroll
          for (int rr = 0; rr < 4; rr++) {
            const float pv = __builtin_amdgcn_exp2f(zz[rr]);
            psB += pv;
            paB[u * 4 + rr] = (__bf16)pv;
          }
        }
      }

      // ---- PV: V fragments loaded once, feed both q-tiles' MFMAs ----
#pragma unroll
      for (int nt = 0; nt < 4; nt++) {
        const int d = nt * 16 + l15;
        const int x0 = (sp * 4 + (quad >> 1)) ^ (d & 7);
        const int x1 = (sp * 4 + 2 + (quad >> 1)) ^ (d & 7);
        union { bf16x8 v8; bf16x4 v4[2]; } uv;
        uv.v4[0] = *(const bf16x4*)&vbuf[cur][(d * 8 + x0) * 8 + (quad & 1) * 4];
        uv.v4[1] = *(const bf16x4*)&vbuf[cur][(d * 8 + x1) * 8 + (quad & 1) * 4];
        oA[nt] = MFMA16(paA, uv.v8, oA[nt]);
        if (doB) oB[nt] = MFMA16(paB, uv.v8, oB[nt]);
      }
    }

    asm volatile("s_waitcnt lgkmcnt(0)" ::: "memory");   // my LDS reads retired
    __builtin_amdgcn_sched_barrier(0);                   // rule 18
    __builtin_amdgcn_s_barrier();                        // buffer may be overwritten next iter
  }

  // ---- epilogues (A then B): one row-sum reduction + normalized store ----
  const int b = bh >> 4, h = bh & 15;

  psA += __shfl_xor(psA, 16);
  psA += __shfl_xor(psA, 32);
  const float invA = 1.f / psA;
#pragma unroll
  for (int rr = 0; rr < 4; rr++) {
    const float inv = __shfl(invA, (lane & 48) + quad * 4 + rr);
    const int row = qtA * 64 + w * 16 + quad * 4 + rr;
#pragma unroll
    for (int nt = 0; nt < 4; nt++) {
      const int col = h * 64 + nt * 16 + l15;
      ctx[((size_t)b * L + row) * 1024 + col] = (__bf16)(oA[nt][rr] * inv);
    }
  }

  psB += __shfl_xor(psB, 16);
  psB += __shfl_xor(psB, 32);
  const float invB = 1.f / psB;
#pragma unroll
  for (int rr = 0; rr < 4; rr++) {
    const float inv = __shfl(invB, (lane & 48) + quad * 4 + rr);
    const int row = qtB * 64 + w * 16 + quad * 4 + rr;
#pragma unroll
    for (int nt = 0; nt < 4; nt++) {
      const int col = h * 64 + nt * 16 + l15;
      ctx[((size_t)b * L + row) * 1024 + col] = (__bf16)(oB[nt][rr] * inv);
    }
  }
}

// ---------------------------------------------------------------------------
extern "C" void kernel_launch(void* const* d_in, const int* in_sizes, int n_in,
                              void* d_out, int out_size, void* d_ws, size_t ws_size,
                              hipStream_t stream) {
  const float* x_q = (const float*)d_in[0];
  const float* x_k = (const float*)d_in[1];
  const float* x_v = (const float*)d_in[2];
  const float* Wq  = (const float*)d_in[3];
  const float* bq  = (const float*)d_in[4];
  const float* Wk  = (const float*)d_in[5];
  const float* bk  = (const float*)d_in[6];
  const float* Wv  = (const float*)d_in[7];
  const float* bv  = (const float*)d_in[8];
  const float* Wo  = (const float*)d_in[9];
  const float* bo  = (const float*)d_in[10];

  char* ws = (char*)d_ws;
  __bf16* xc  = (__bf16*)ws;                          // 3 x [4096][1024] bf16 (24 MB), dead after gemm_proj
  __bf16* wt  = (__bf16*)(ws + ((size_t)24 << 20));   // 4 x 1024x1024 bf16    (8 MB)
  __bf16* qkv = (__bf16*)(ws + ((size_t)32 << 20));   // q,k [bh][l][d]; vT [bh][d][l] (24 MB)
  __bf16* ctx = (__bf16*)ws;                          // [B,L,1024] (8 MB) — reuses xc region
  __bf16* qp  = qkv;
  __bf16* kp  = qkv + (size_t)BB * L * D;
  __bf16* vtp = qkv + (size_t)2 * BB * L * D;

  cvt_x<<<dim3(1024, 1, 3), 256, 0, stream>>>(x_q, x_k, x_v, xc);
  transpose_w<<<dim3(32, 32, 4), dim3(32, 8), 0, stream>>>(Wq, Wk, Wv, Wo, wt);
  gemm_proj<<<dim3(8, 32, 3), 256, 0, stream>>>(xc, wt, bq, bk, bv, qkv);
  flash_attn<<<dim3(16, 32), 256, 0, stream>>>(qp, kp, vtp, ctx);
  gemm_o<<<dim3(8, 32), 256, 0, stream>>>(ctx, wt + (size_t)3 * D * D, bo, (float*)d_out);
}

// Round 9
// 211.464 us; speedup vs baseline: 1.0098x; 1.0098x over previous
//
#include <hip/hip_runtime.h>
#include <hip/hip_bf16.h>

typedef __bf16 bf16x8 __attribute__((ext_vector_type(8)));
typedef __bf16 bf16x4 __attribute__((ext_vector_type(4)));
typedef float floatx4 __attribute__((ext_vector_type(4)));

#define MFMA16(a, b, c) __builtin_amdgcn_mfma_f32_16x16x32_bf16(a, b, c, 0, 0, 0)
#define AS1 __attribute__((address_space(1)))
#define AS3 __attribute__((address_space(3)))

constexpr int D = 1024;
constexpr int L = 2048;
constexpr int BB = 2;
constexpr int DH = 64;
constexpr float NEG_BIG = -1e30f;                 // exp2 -> 0, fast-math safe
constexpr float SCALE_LOG2E = 0.125f * 1.4426950408889634f;  // folded into Q projection

// async global->LDS, 16B per lane (dest = wave-uniform base + lane*16)
__device__ __forceinline__ void gld16(const __bf16* g, __bf16* l) {
  __builtin_amdgcn_global_load_lds((AS1 void*)g, (AS3 void*)l, 16, 0, 0);
}

// ---------------------------------------------------------------------------
// Convert fp32 x (q,k,v inputs) -> canonical bf16 [3][4096][1024]
// ---------------------------------------------------------------------------
__global__ __launch_bounds__(256) void cvt_x(const float* __restrict__ xq, const float* __restrict__ xk,
                                             const float* __restrict__ xv, __bf16* __restrict__ out) {
  const int z = blockIdx.z;
  const float* src = z == 0 ? xq : z == 1 ? xk : xv;
  __bf16* dst = out + (size_t)z * BB * L * D;
  const int N = BB * L * D;
  const int stride = gridDim.x * 256 * 4;
  for (int i = (blockIdx.x * 256 + threadIdx.x) * 4; i < N; i += stride) {
    float4 f = *(const float4*)&src[i];
    bf16x4 b = {(__bf16)f.x, (__bf16)f.y, (__bf16)f.z, (__bf16)f.w};
    *(bf16x4*)&dst[i] = b;
  }
}

// ---------------------------------------------------------------------------
// Transpose 4 fp32 weight matrices W[K][N] -> canonical bf16 Wt[N][K]
// ---------------------------------------------------------------------------
__global__ void transpose_w(const float* __restrict__ w0, const float* __restrict__ w1,
                            const float* __restrict__ w2, const float* __restrict__ w3,
                            __bf16* __restrict__ out) {
  __shared__ __bf16 tile[32][33];
  int mat = blockIdx.z;
  const float* src = mat == 0 ? w0 : mat == 1 ? w1 : mat == 2 ? w2 : w3;
  __bf16* dst = out + (size_t)mat * D * D;
  int bx = blockIdx.x * 32, by = blockIdx.y * 32;
  int tx = threadIdx.x, ty = threadIdx.y;  // block (32, 8)
#pragma unroll
  for (int i = 0; i < 32; i += 8)
    tile[ty + i][tx] = (__bf16)src[(size_t)(by + ty + i) * D + bx + tx];
  __syncthreads();
#pragma unroll
  for (int i = 0; i < 32; i += 8)
    dst[(size_t)(bx + ty + i) * D + by + tx] = tile[tx][ty + i];
}

// ---------------------------------------------------------------------------
// GEMM main loop: T4 counted-vmcnt 2-phase pipeline (frozen from R5).
// 128x128 tile, BK=32, double-buffered LDS in sm[0..16383].
// LDS swizzle (both-sides, rule 21): 2-row-granular XOR, 2-way = free.
// ---------------------------------------------------------------------------
__device__ __forceinline__ void stage32(const __bf16* __restrict__ A, const __bf16* __restrict__ Bt,
                                        __bf16* sA, __bf16* sB, int m0, int n0, int kb,
                                        int r, int sc, int dst) {
  // thread t: r = t>>2 (0..63), sc = ((t&3) ^ ((r>>1)&3))*8, dst = t*8
  gld16(&A[(size_t)(m0 + r) * 1024 + kb + sc],       &sA[dst]);
  gld16(&A[(size_t)(m0 + 64 + r) * 1024 + kb + sc],  &sA[2048 + dst]);  // (64+r)>>1 &3 == (r>>1)&3
  gld16(&Bt[(size_t)(n0 + r) * 1024 + kb + sc],      &sB[dst]);
  gld16(&Bt[(size_t)(n0 + 64 + r) * 1024 + kb + sc], &sB[2048 + dst]);
}

__device__ __forceinline__ void gemm_core(const __bf16* __restrict__ A, const __bf16* __restrict__ Bt,
                                          __bf16* sm, int m0, int n0, int wm, int wn,
                                          int l15, int quad, int t, floatx4 (&acc)[4][4]) {
  const int r = t >> 2;                         // 0..63
  const int sc = ((t & 3) ^ ((r >> 1) & 3)) * 8;
  const int dst = t * 8;
  const int sw2 = (l15 >> 1) & 3;               // (row>>1)&3 for all frag rows

  // prologue: stage K-step 0 into buffer 0
  stage32(A, Bt, sm, sm + 8192, m0, n0, 0, r, sc, dst);

  int cur = 0;
  for (int kb = 0; kb < 1024; kb += 32) {
    if (kb + 32 < 1024) {
      stage32(A, Bt, sm + (cur ^ 1) * 4096, sm + 8192 + (cur ^ 1) * 4096, m0, n0, kb + 32, r, sc, dst);
      asm volatile("s_waitcnt vmcnt(4)" ::: "memory");   // tile kb landed; kb+32 stays in flight
    } else {
      asm volatile("s_waitcnt vmcnt(0)" ::: "memory");   // last tile
    }
    __builtin_amdgcn_s_barrier();                        // all waves: tile kb resident

    const __bf16* sAc = sm + cur * 4096;
    const __bf16* sBc = sm + 8192 + cur * 4096;
    bf16x8 af[4], bf_[4];
#pragma unroll
    for (int i = 0; i < 4; i++) {
      const int row = wm * 64 + i * 16 + l15;
      af[i] = *(const bf16x8*)&sAc[(row * 4 + (quad ^ sw2)) * 8];
    }
#pragma unroll
    for (int j = 0; j < 4; j++) {
      const int row = wn * 64 + j * 16 + l15;
      bf_[j] = *(const bf16x8*)&sBc[(row * 4 + (quad ^ sw2)) * 8];
    }
    asm volatile("s_waitcnt lgkmcnt(0)" ::: "memory");   // my reads retired
    __builtin_amdgcn_sched_barrier(0);                   // rule 18: no MFMA hoist
    __builtin_amdgcn_s_barrier();                        // all reads retired -> overwrite ok

#pragma unroll
    for (int i = 0; i < 4; i++)
#pragma unroll
      for (int j = 0; j < 4; j++)
        acc[i][j] = MFMA16(af[i], bf_[j], acc[i][j]);    // overlaps next stage issue

    cur ^= 1;
  }
}

// ---------------------------------------------------------------------------
// QKV projection. z=0: Q scaled, [bh][l][dh]. z=1: K, [bh][l][dh].
// z=2: V TRANSPOSED [bh][dh][L]. XCD-swizzled (FETCH 101.5 -> 22.7 MB, R2).
// Epilogue: LDS-repack + coalesced 16B stores (R6 win: total 228.6 -> 206.1).
// ---------------------------------------------------------------------------
__global__ __launch_bounds__(256, 3) void gemm_proj(const __bf16* __restrict__ xc, const __bf16* __restrict__ wt,
                                                    const float* __restrict__ bq, const float* __restrict__ bk,
                                                    const float* __restrict__ bv, __bf16* __restrict__ qkv) {
  __shared__ __align__(16) __bf16 smem[17408];  // K-loop: 16384; epilogue T: 128x136

  const int flat = (blockIdx.z * 32 + blockIdx.y) * 8 + blockIdx.x;
  const int s = (flat & 7) * 96 + (flat >> 3);
  const int z = s >> 8;           // s / 256
  const int rem = s & 255;
  const int by = rem >> 3, bx = rem & 7;

  const __bf16* A = xc + (size_t)z * BB * L * D;
  const __bf16* Bt = wt + (size_t)z * D * D;
  const float* bias = z == 0 ? bq : z == 1 ? bk : bv;
  __bf16* dst = qkv + (size_t)z * BB * L * D;

  const int t = threadIdx.x;
  const int lane = t & 63;
  const int w = t >> 6;
  const int wm = w >> 1, wn = w & 1;
  const int l15 = lane & 15, quad = lane >> 4;
  const int m0 = by * 128, n0 = bx * 128;

  floatx4 acc[4][4];
#pragma unroll
  for (int i = 0; i < 4; i++)
#pragma unroll
    for (int j = 0; j < 4; j++) acc[i][j] = (floatx4){0.f, 0.f, 0.f, 0.f};

  gemm_core(A, Bt, smem, m0, n0, wm, wn, l15, quad, t, acc);

  float bvv[4];
#pragma unroll
  for (int j = 0; j < 4; j++) bvv[j] = bias[n0 + wn * 64 + j * 16 + l15];

  // ---- phase 1: C-tile -> LDS (K-loop buffers dead after final barrier) ----
  constexpr int TP = 136;                       // pad: row stride 272 B spreads banks
  __bf16* T = smem;
  if (z < 2) {
#pragma unroll
    for (int i = 0; i < 4; i++) {
      const int mrowb = wm * 64 + i * 16 + quad * 4;
#pragma unroll
      for (int j = 0; j < 4; j++) {
        const int ccol = wn * 64 + j * 16 + l15;
#pragma unroll
        for (int rr = 0; rr < 4; rr++) {
          float val = acc[i][j][rr] + bvv[j];
          if (z == 0) val *= SCALE_LOG2E;
          T[(mrowb + rr) * TP + ccol] = (__bf16)val;
        }
      }
    }
  } else {
#pragma unroll
    for (int i = 0; i < 4; i++) {
      const int mrowb = wm * 64 + i * 16 + quad * 4;
#pragma unroll
      for (int j = 0; j < 4; j++) {
        const int ccol = wn * 64 + j * 16 + l15;
        bf16x4 v4;
#pragma unroll
        for (int rr = 0; rr < 4; rr++) v4[rr] = (__bf16)(acc[i][j][rr] + bvv[j]);
        *(bf16x4*)&T[ccol * TP + mrowb] = v4;
      }
    }
  }
  __syncthreads();

  // ---- phase 2: coalesced 16B stores (2048 chunks, 8 per thread) ----
  const int b = m0 >> 11;                       // tile never crosses batch boundary
  const int l0 = m0 & 2047;
  if (z < 2) {
#pragma unroll
    for (int sH = 0; sH < 8; sH++) {
      const int c = sH * 256 + t;
      const int mrow = c >> 4, k16 = c & 15;
      const int h = (n0 >> 6) + (k16 >> 3);
      const int d0 = (k16 & 7) * 8;
      bf16x8 v = *(const bf16x8*)&T[mrow * TP + k16 * 8];
      *(bf16x8*)&dst[((size_t)(b * 16 + h) * 2048 + l0 + mrow) * 64 + d0] = v;
    }
  } else {
    const int R0 = (b * 16 + (n0 >> 6)) * 64;   // V^T rows for this col-panel are contiguous
#pragma unroll
    for (int sH = 0; sH < 8; sH++) {
      const int c = sH * 256 + t;
      const int ccol = c >> 4, k16 = c & 15;
      bf16x8 v = *(const bf16x8*)&T[ccol * TP + k16 * 8];
      *(bf16x8*)&dst[(size_t)(R0 + ccol) * 2048 + l0 + k16 * 8] = v;
    }
  }
}

// ---------------------------------------------------------------------------
// Output projection: ctx bf16 [4096][1024] @ Wo^T + bo -> fp32 out
// ---------------------------------------------------------------------------
__global__ __launch_bounds__(256, 3) void gemm_o(const __bf16* __restrict__ ctx, const __bf16* __restrict__ wto,
                                                 const float* __restrict__ bo, float* __restrict__ out) {
  __shared__ __align__(16) __bf16 smem[16384];

  const int flat = blockIdx.y * 8 + blockIdx.x;      // grid (8,32) = 256 blocks
  const int s = (flat & 7) * 32 + (flat >> 3);
  const int by = s >> 3, bx = s & 7;

  const int t = threadIdx.x;
  const int lane = t & 63;
  const int w = t >> 6;
  const int wm = w >> 1, wn = w & 1;
  const int l15 = lane & 15, quad = lane >> 4;
  const int m0 = by * 128, n0 = bx * 128;

  floatx4 acc[4][4];
#pragma unroll
  for (int i = 0; i < 4; i++)
#pragma unroll
    for (int j = 0; j < 4; j++) acc[i][j] = (floatx4){0.f, 0.f, 0.f, 0.f};

  gemm_core(ctx, wto, smem, m0, n0, wm, wn, l15, quad, t, acc);

  float bvv[4];
#pragma unroll
  for (int j = 0; j < 4; j++) bvv[j] = bo[n0 + wn * 64 + j * 16 + l15];

#pragma unroll
  for (int i = 0; i < 4; i++) {
    const int rowb = m0 + wm * 64 + i * 16 + quad * 4;
#pragma unroll
    for (int j = 0; j < 4; j++) {
      const int col = n0 + wn * 64 + j * 16 + l15;
#pragma unroll
      for (int rr = 0; rr < 4; rr++)
        out[(size_t)(rowb + rr) * 1024 + col] = acc[i][j][rr] + bvv[j];
    }
  }
}

// ---------------------------------------------------------------------------
// Flash attention, causal. q,k in [bh][L][64]; vT in [bh][64][L] (all bf16).
// Q pre-scaled by 0.125*log2e; no max subtraction (|S2|<~9 bounded), row sums
// deferred -> k-tile order irrelevant (pure accumulation).
//
// R9: throughput law measured across R6/R7/R8: time = (updates/CU) x 0.70us,
// where update = one 64q x 64k tile; LDS frag reads dominate the 0.70us
// (MFMA only 5%). R8 proved a SECOND q-update sharing the same K/V frags is
// ~free. So: make every iteration dual.
//   Block owns a CONTIGUOUS 128-row q-super-tile P: sub-tiles qtB=2P (lo),
//   qtA=2P+1 (hi). One kt sweep 0..qtA: hi active every iter, lo all but the
//   last -> dual on (2P+1)/(2P+2) iters, K/V frag reads per update HALVED.
//   Two passes P=p then P=15-p -> every block exactly 34 iters / 66 updates
//   (uniform). Grid (8,32)=256 blocks = 1/CU; dual-stream ILP inside each
//   wave covers latency without a co-resident block.
//   XCD swizzle: bh = (flat&7)*4 + (flat>>6) puts each bh's 8 blocks on one
//   XCD -> 4 bh x 512KB K/V = 2MB resident per 4MB L2.
// ---------------------------------------------------------------------------
__global__ __launch_bounds__(256, 2) void flash_attn(const __bf16* __restrict__ q, const __bf16* __restrict__ k,
                                                     const __bf16* __restrict__ vT, __bf16* __restrict__ ctx) {
  __shared__ __align__(16) __bf16 kbuf[2][4096];  // K tile: 64 rows x 64 d, swizzled
  __shared__ __align__(16) __bf16 vbuf[2][4096];  // V^T tile: 64 d x 64 kpos, swizzled

  const int t = threadIdx.x;
  const int lane = t & 63;
  const int w = t >> 6;                 // wave 0..3
  const int l15 = lane & 15, quad = lane >> 4;

  const int flat = blockIdx.y * 8 + blockIdx.x;    // 0..255
  const int bh = (flat & 7) * 4 + (flat >> 6);     // same-bh blocks share an XCD
  const int p = (flat >> 3) & 7;                   // pair index 0..7

  const __bf16* qb = q + (size_t)bh * L * DH;
  const __bf16* kb_ = k + (size_t)bh * L * DH;
  const __bf16* vb = vT + (size_t)bh * DH * L;

  // staging map: thread t covers LDS chunks c0 = t, c1 = 256+t (16B each).
  // chunk c holds row r = c>>3, swizzled sub-chunk (c&7) -> col8 = (c&7)^(r&7)
  const int c0 = t, c1 = 256 + t;
  const int kr0 = c0 >> 3, kd0 = ((c0 & 7) ^ (kr0 & 7)) * 8;
  const int kr1 = c1 >> 3, kd1 = ((c1 & 7) ^ (kr1 & 7)) * 8;

  const int b = bh >> 4, h = bh & 15;

#pragma unroll 1
  for (int pass = 0; pass < 2; ++pass) {
    const int P = pass == 0 ? p : 15 - p;   // p in [0,7], 15-p in [8,15]: all 16 covered
    const int qtA = 2 * P + 1;              // hi sub-tile (long): active all iters
    const int qtB = 2 * P;                  // lo sub-tile: active all but last iter

    const int qrA = qtA * 64 + w * 16 + l15;
    const int qrB = qtB * 64 + w * 16 + l15;
    const bf16x8 aqA0 = *(const bf16x8*)&qb[(size_t)qrA * 64 + quad * 8];
    const bf16x8 aqA1 = *(const bf16x8*)&qb[(size_t)qrA * 64 + 32 + quad * 8];
    const bf16x8 aqB0 = *(const bf16x8*)&qb[(size_t)qrB * 64 + quad * 8];
    const bf16x8 aqB1 = *(const bf16x8*)&qb[(size_t)qrB * 64 + 32 + quad * 8];

    floatx4 oA[4], oB[4];
#pragma unroll
    for (int nt = 0; nt < 4; nt++) {
      oA[nt] = (floatx4){0.f, 0.f, 0.f, 0.f};
      oB[nt] = (floatx4){0.f, 0.f, 0.f, 0.f};
    }
    float psA = 0.f, psB = 0.f;

    // preload k-tile 0 into buf 0 (iter 0's vmcnt(4) waits for it; pass 1:
    // prior pass's final lgkmcnt(0)+barrier guarantees all LDS reads retired)
    gld16(&kb_[(size_t)kr0 * 64 + kd0], &kbuf[0][c0 * 8]);
    gld16(&kb_[(size_t)kr1 * 64 + kd1], &kbuf[0][c1 * 8]);
    gld16(&vb[(size_t)kr0 * L + kd0],   &vbuf[0][c0 * 8]);
    gld16(&vb[(size_t)kr1 * L + kd1],   &vbuf[0][c1 * 8]);

#pragma unroll 1
    for (int it = 0; it <= qtA; ++it) {
      const int cur = it & 1;
      const int kt = it * 64;

      // ---- stage k-tile it+1; wait ONLY tile it (counted vmcnt, T4) ----
      if (it < qtA) {
        const int ktn = kt + 64;
        gld16(&kb_[(size_t)(ktn + kr0) * 64 + kd0], &kbuf[cur ^ 1][c0 * 8]);
        gld16(&kb_[(size_t)(ktn + kr1) * 64 + kd1], &kbuf[cur ^ 1][c1 * 8]);
        gld16(&vb[(size_t)kr0 * L + ktn + kd0],     &vbuf[cur ^ 1][c0 * 8]);
        gld16(&vb[(size_t)kr1 * L + ktn + kd1],     &vbuf[cur ^ 1][c1 * 8]);
        asm volatile("s_waitcnt vmcnt(4)" ::: "memory");   // tile it landed; it+1 in flight
      } else {
        asm volatile("s_waitcnt vmcnt(0)" ::: "memory");   // last tile
      }
      __builtin_amdgcn_s_barrier();                        // all waves: tile it resident

      const bool diagA = (it == qtA);
      const bool doB   = (it <= qtB);      // all but the last iteration
      const bool diagB = (it == qtB);

#pragma unroll
      for (int sp = 0; sp < 2; ++sp) {      // two 32-wide kpos windows
        // ---- K fragments (shared by both q-sub-tiles) ----
        bf16x8 kf0[2], kf1[2];
#pragma unroll
        for (int u = 0; u < 2; ++u) {
          const int kr = (2 * sp + u) * 16 + l15;
          kf0[u] = *(const bf16x8*)&kbuf[cur][(kr * 8 + (quad ^ (kr & 7))) * 8];
          kf1[u] = *(const bf16x8*)&kbuf[cur][(kr * 8 + ((quad + 4) ^ (kr & 7))) * 8];
        }

        // ---- S^T, mask, P=exp2: sub-tile A (hi) ----
        bf16x8 paA;
#pragma unroll
        for (int u = 0; u < 2; ++u) {
          floatx4 zz = (floatx4){0.f, 0.f, 0.f, 0.f};
          zz = MFMA16(kf0[u], aqA0, zz);
          zz = MFMA16(kf1[u], aqA1, zz);
          if (diagA) {
            const int kgb = kt + (2 * sp + u) * 16 + quad * 4;
#pragma unroll
            for (int rr = 0; rr < 4; rr++)
              if (kgb + rr > qrA) zz[rr] = NEG_BIG;
          }
#pragma unroll
          for (int rr = 0; rr < 4; rr++) {
            const float pv = __builtin_amdgcn_exp2f(zz[rr]);
            psA += pv;
            paA[u * 4 + rr] = (__bf16)pv;
          }
        }

        // ---- sub-tile B (lo), block-uniform skip at the last iter ----
        bf16x8 paB;
        if (doB) {
#pragma unroll
          for (int u = 0; u < 2; ++u) {
            floatx4 zz = (floatx4){0.f, 0.f, 0.f, 0.f};
            zz = MFMA16(kf0[u], aqB0, zz);
            zz = MFMA16(kf1[u], aqB1, zz);
            if (diagB) {
              const int kgb = kt + (2 * sp + u) * 16 + quad * 4;
#pragma unroll
              for (int rr = 0; rr < 4; rr++)
                if (kgb + rr > qrB) zz[rr] = NEG_BIG;
            }
#pragma unroll
            for (int rr = 0; rr < 4; rr++) {
              const float pv = __builtin_amdgcn_exp2f(zz[rr]);
              psB += pv;
              paB[u * 4 + rr] = (__bf16)pv;
            }
          }
        }

        // ---- PV: V fragments loaded once, feed both sub-tiles ----
#pragma unroll
        for (int nt = 0; nt < 4; nt++) {
          const int d = nt * 16 + l15;
          const int x0 = (sp * 4 + (quad >> 1)) ^ (d & 7);
          const int x1 = (sp * 4 + 2 + (quad >> 1)) ^ (d & 7);
          union { bf16x8 v8; bf16x4 v4[2]; } uv;
          uv.v4[0] = *(const bf16x4*)&vbuf[cur][(d * 8 + x0) * 8 + (quad & 1) * 4];
          uv.v4[1] = *(const bf16x4*)&vbuf[cur][(d * 8 + x1) * 8 + (quad & 1) * 4];
          oA[nt] = MFMA16(paA, uv.v8, oA[nt]);
          if (doB) oB[nt] = MFMA16(paB, uv.v8, oB[nt]);
        }
      }

      asm volatile("s_waitcnt lgkmcnt(0)" ::: "memory");   // my LDS reads retired
      __builtin_amdgcn_sched_barrier(0);                   // rule 18
      __builtin_amdgcn_s_barrier();                        // buffer may be overwritten next iter
    }

    // ---- epilogues (A then B): row-sum reduce + normalized store ----
    psA += __shfl_xor(psA, 16);
    psA += __shfl_xor(psA, 32);
    const float invA = 1.f / psA;
#pragma unroll
    for (int rr = 0; rr < 4; rr++) {
      const float inv = __shfl(invA, (lane & 48) + quad * 4 + rr);
      const int row = qtA * 64 + w * 16 + quad * 4 + rr;
#pragma unroll
      for (int nt = 0; nt < 4; nt++) {
        const int col = h * 64 + nt * 16 + l15;
        ctx[((size_t)b * L + row) * 1024 + col] = (__bf16)(oA[nt][rr] * inv);
      }
    }

    psB += __shfl_xor(psB, 16);
    psB += __shfl_xor(psB, 32);
    const float invB = 1.f / psB;
#pragma unroll
    for (int rr = 0; rr < 4; rr++) {
      const float inv = __shfl(invB, (lane & 48) + quad * 4 + rr);
      const int row = qtB * 64 + w * 16 + quad * 4 + rr;
#pragma unroll
      for (int nt = 0; nt < 4; nt++) {
        const int col = h * 64 + nt * 16 + l15;
        ctx[((size_t)b * L + row) * 1024 + col] = (__bf16)(oB[nt][rr] * inv);
      }
    }
  }
}

// ---------------------------------------------------------------------------
extern "C" void kernel_launch(void* const* d_in, const int* in_sizes, int n_in,
                              void* d_out, int out_size, void* d_ws, size_t ws_size,
                              hipStream_t stream) {
  const float* x_q = (const float*)d_in[0];
  const float* x_k = (const float*)d_in[1];
  const float* x_v = (const float*)d_in[2];
  const float* Wq  = (const float*)d_in[3];
  const float* bq  = (const float*)d_in[4];
  const float* Wk  = (const float*)d_in[5];
  const float* bk  = (const float*)d_in[6];
  const float* Wv  = (const float*)d_in[7];
  const float* bv  = (const float*)d_in[8];
  const float* Wo  = (const float*)d_in[9];
  const float* bo  = (const float*)d_in[10];

  char* ws = (char*)d_ws;
  __bf16* xc  = (__bf16*)ws;                          // 3 x [4096][1024] bf16 (24 MB), dead after gemm_proj
  __bf16* wt  = (__bf16*)(ws + ((size_t)24 << 20));   // 4 x 1024x1024 bf16    (8 MB)
  __bf16* qkv = (__bf16*)(ws + ((size_t)32 << 20));   // q,k [bh][l][d]; vT [bh][d][l] (24 MB)
  __bf16* ctx = (__bf16*)ws;                          // [B,L,1024] (8 MB) — reuses xc region
  __bf16* qp  = qkv;
  __bf16* kp  = qkv + (size_t)BB * L * D;
  __bf16* vtp = qkv + (size_t)2 * BB * L * D;

  cvt_x<<<dim3(1024, 1, 3), 256, 0, stream>>>(x_q, x_k, x_v, xc);
  transpose_w<<<dim3(32, 32, 4), dim3(32, 8), 0, stream>>>(Wq, Wk, Wv, Wo, wt);
  gemm_proj<<<dim3(8, 32, 3), 256, 0, stream>>>(xc, wt, bq, bk, bv, qkv);
  flash_attn<<<dim3(8, 32), 256, 0, stream>>>(qp, kp, vtp, ctx);
  gemm_o<<<dim3(8, 32), 256, 0, stream>>>(ctx, wt + (size_t)3 * D * D, bo, (float*)d_out);
}

// Round 10
// 206.153 us; speedup vs baseline: 1.0358x; 1.0258x over previous
//
#include <hip/hip_runtime.h>
#include <hip/hip_bf16.h>

typedef __bf16 bf16x8 __attribute__((ext_vector_type(8)));
typedef __bf16 bf16x4 __attribute__((ext_vector_type(4)));
typedef float floatx4 __attribute__((ext_vector_type(4)));

#define MFMA16(a, b, c) __builtin_amdgcn_mfma_f32_16x16x32_bf16(a, b, c, 0, 0, 0)
#define AS1 __attribute__((address_space(1)))
#define AS3 __attribute__((address_space(3)))

constexpr int D = 1024;
constexpr int L = 2048;
constexpr int BB = 2;
constexpr int DH = 64;
constexpr float NEG_BIG = -1e30f;                 // exp2 -> 0, fast-math safe
constexpr float SCALE_LOG2E = 0.125f * 1.4426950408889634f;  // folded into Q projection

// async global->LDS, 16B per lane (dest = wave-uniform base + lane*16)
__device__ __forceinline__ void gld16(const __bf16* g, __bf16* l) {
  __builtin_amdgcn_global_load_lds((AS1 void*)g, (AS3 void*)l, 16, 0, 0);
}

// ---------------------------------------------------------------------------
// Convert fp32 x (q,k,v inputs) -> canonical bf16 [3][4096][1024]
// ---------------------------------------------------------------------------
__global__ __launch_bounds__(256) void cvt_x(const float* __restrict__ xq, const float* __restrict__ xk,
                                             const float* __restrict__ xv, __bf16* __restrict__ out) {
  const int z = blockIdx.z;
  const float* src = z == 0 ? xq : z == 1 ? xk : xv;
  __bf16* dst = out + (size_t)z * BB * L * D;
  const int N = BB * L * D;
  const int stride = gridDim.x * 256 * 4;
  for (int i = (blockIdx.x * 256 + threadIdx.x) * 4; i < N; i += stride) {
    float4 f = *(const float4*)&src[i];
    bf16x4 b = {(__bf16)f.x, (__bf16)f.y, (__bf16)f.z, (__bf16)f.w};
    *(bf16x4*)&dst[i] = b;
  }
}

// ---------------------------------------------------------------------------
// Transpose 4 fp32 weight matrices W[K][N] -> canonical bf16 Wt[N][K]
// ---------------------------------------------------------------------------
__global__ void transpose_w(const float* __restrict__ w0, const float* __restrict__ w1,
                            const float* __restrict__ w2, const float* __restrict__ w3,
                            __bf16* __restrict__ out) {
  __shared__ __bf16 tile[32][33];
  int mat = blockIdx.z;
  const float* src = mat == 0 ? w0 : mat == 1 ? w1 : mat == 2 ? w2 : w3;
  __bf16* dst = out + (size_t)mat * D * D;
  int bx = blockIdx.x * 32, by = blockIdx.y * 32;
  int tx = threadIdx.x, ty = threadIdx.y;  // block (32, 8)
#pragma unroll
  for (int i = 0; i < 32; i += 8)
    tile[ty + i][tx] = (__bf16)src[(size_t)(by + ty + i) * D + bx + tx];
  __syncthreads();
#pragma unroll
  for (int i = 0; i < 32; i += 8)
    dst[(size_t)(bx + ty + i) * D + by + tx] = tile[tx][ty + i];
}

// ---------------------------------------------------------------------------
// GEMM main loop: T4 counted-vmcnt 2-phase pipeline (frozen from R5).
// 128x128 tile, BK=32, double-buffered LDS in sm[0..16383].
// LDS swizzle (both-sides, rule 21): 2-row-granular XOR, 2-way = free.
// ---------------------------------------------------------------------------
__device__ __forceinline__ void stage32(const __bf16* __restrict__ A, const __bf16* __restrict__ Bt,
                                        __bf16* sA, __bf16* sB, int m0, int n0, int kb,
                                        int r, int sc, int dst) {
  // thread t: r = t>>2 (0..63), sc = ((t&3) ^ ((r>>1)&3))*8, dst = t*8
  gld16(&A[(size_t)(m0 + r) * 1024 + kb + sc],       &sA[dst]);
  gld16(&A[(size_t)(m0 + 64 + r) * 1024 + kb + sc],  &sA[2048 + dst]);  // (64+r)>>1 &3 == (r>>1)&3
  gld16(&Bt[(size_t)(n0 + r) * 1024 + kb + sc],      &sB[dst]);
  gld16(&Bt[(size_t)(n0 + 64 + r) * 1024 + kb + sc], &sB[2048 + dst]);
}

__device__ __forceinline__ void gemm_core(const __bf16* __restrict__ A, const __bf16* __restrict__ Bt,
                                          __bf16* sm, int m0, int n0, int wm, int wn,
                                          int l15, int quad, int t, floatx4 (&acc)[4][4]) {
  const int r = t >> 2;                         // 0..63
  const int sc = ((t & 3) ^ ((r >> 1) & 3)) * 8;
  const int dst = t * 8;
  const int sw2 = (l15 >> 1) & 3;               // (row>>1)&3 for all frag rows

  // prologue: stage K-step 0 into buffer 0
  stage32(A, Bt, sm, sm + 8192, m0, n0, 0, r, sc, dst);

  int cur = 0;
  for (int kb = 0; kb < 1024; kb += 32) {
    if (kb + 32 < 1024) {
      stage32(A, Bt, sm + (cur ^ 1) * 4096, sm + 8192 + (cur ^ 1) * 4096, m0, n0, kb + 32, r, sc, dst);
      asm volatile("s_waitcnt vmcnt(4)" ::: "memory");   // tile kb landed; kb+32 stays in flight
    } else {
      asm volatile("s_waitcnt vmcnt(0)" ::: "memory");   // last tile
    }
    __builtin_amdgcn_s_barrier();                        // all waves: tile kb resident

    const __bf16* sAc = sm + cur * 4096;
    const __bf16* sBc = sm + 8192 + cur * 4096;
    bf16x8 af[4], bf_[4];
#pragma unroll
    for (int i = 0; i < 4; i++) {
      const int row = wm * 64 + i * 16 + l15;
      af[i] = *(const bf16x8*)&sAc[(row * 4 + (quad ^ sw2)) * 8];
    }
#pragma unroll
    for (int j = 0; j < 4; j++) {
      const int row = wn * 64 + j * 16 + l15;
      bf_[j] = *(const bf16x8*)&sBc[(row * 4 + (quad ^ sw2)) * 8];
    }
    asm volatile("s_waitcnt lgkmcnt(0)" ::: "memory");   // my reads retired
    __builtin_amdgcn_sched_barrier(0);                   // rule 18: no MFMA hoist
    __builtin_amdgcn_s_barrier();                        // all reads retired -> overwrite ok

#pragma unroll
    for (int i = 0; i < 4; i++)
#pragma unroll
      for (int j = 0; j < 4; j++)
        acc[i][j] = MFMA16(af[i], bf_[j], acc[i][j]);    // overlaps next stage issue

    cur ^= 1;
  }
}

// ---------------------------------------------------------------------------
// QKV projection. z=0: Q scaled, [bh][l][dh]. z=1: K, [bh][l][dh].
// z=2: V TRANSPOSED [bh][dh][L]. XCD-swizzled (FETCH 101.5 -> 22.7 MB, R2).
// Epilogue: LDS-repack + coalesced 16B stores (R6 win: total 228.6 -> 206.1).
// ---------------------------------------------------------------------------
__global__ __launch_bounds__(256, 3) void gemm_proj(const __bf16* __restrict__ xc, const __bf16* __restrict__ wt,
                                                    const float* __restrict__ bq, const float* __restrict__ bk,
                                                    const float* __restrict__ bv, __bf16* __restrict__ qkv) {
  __shared__ __align__(16) __bf16 smem[17408];  // K-loop: 16384; epilogue T: 128x136

  const int flat = (blockIdx.z * 32 + blockIdx.y) * 8 + blockIdx.x;
  const int s = (flat & 7) * 96 + (flat >> 3);
  const int z = s >> 8;           // s / 256
  const int rem = s & 255;
  const int by = rem >> 3, bx = rem & 7;

  const __bf16* A = xc + (size_t)z * BB * L * D;
  const __bf16* Bt = wt + (size_t)z * D * D;
  const float* bias = z == 0 ? bq : z == 1 ? bk : bv;
  __bf16* dst = qkv + (size_t)z * BB * L * D;

  const int t = threadIdx.x;
  const int lane = t & 63;
  const int w = t >> 6;
  const int wm = w >> 1, wn = w & 1;
  const int l15 = lane & 15, quad = lane >> 4;
  const int m0 = by * 128, n0 = bx * 128;

  floatx4 acc[4][4];
#pragma unroll
  for (int i = 0; i < 4; i++)
#pragma unroll
    for (int j = 0; j < 4; j++) acc[i][j] = (floatx4){0.f, 0.f, 0.f, 0.f};

  gemm_core(A, Bt, smem, m0, n0, wm, wn, l15, quad, t, acc);

  float bvv[4];
#pragma unroll
  for (int j = 0; j < 4; j++) bvv[j] = bias[n0 + wn * 64 + j * 16 + l15];

  // ---- phase 1: C-tile -> LDS (K-loop buffers dead after final barrier) ----
  constexpr int TP = 136;                       // pad: row stride 272 B spreads banks
  __bf16* T = smem;
  if (z < 2) {
#pragma unroll
    for (int i = 0; i < 4; i++) {
      const int mrowb = wm * 64 + i * 16 + quad * 4;
#pragma unroll
      for (int j = 0; j < 4; j++) {
        const int ccol = wn * 64 + j * 16 + l15;
#pragma unroll
        for (int rr = 0; rr < 4; rr++) {
          float val = acc[i][j][rr] + bvv[j];
          if (z == 0) val *= SCALE_LOG2E;
          T[(mrowb + rr) * TP + ccol] = (__bf16)val;
        }
      }
    }
  } else {
#pragma unroll
    for (int i = 0; i < 4; i++) {
      const int mrowb = wm * 64 + i * 16 + quad * 4;
#pragma unroll
      for (int j = 0; j < 4; j++) {
        const int ccol = wn * 64 + j * 16 + l15;
        bf16x4 v4;
#pragma unroll
        for (int rr = 0; rr < 4; rr++) v4[rr] = (__bf16)(acc[i][j][rr] + bvv[j]);
        *(bf16x4*)&T[ccol * TP + mrowb] = v4;
      }
    }
  }
  __syncthreads();

  // ---- phase 2: coalesced 16B stores (2048 chunks, 8 per thread) ----
  const int b = m0 >> 11;                       // tile never crosses batch boundary
  const int l0 = m0 & 2047;
  if (z < 2) {
#pragma unroll
    for (int sH = 0; sH < 8; sH++) {
      const int c = sH * 256 + t;
      const int mrow = c >> 4, k16 = c & 15;
      const int h = (n0 >> 6) + (k16 >> 3);
      const int d0 = (k16 & 7) * 8;
      bf16x8 v = *(const bf16x8*)&T[mrow * TP + k16 * 8];
      *(bf16x8*)&dst[((size_t)(b * 16 + h) * 2048 + l0 + mrow) * 64 + d0] = v;
    }
  } else {
    const int R0 = (b * 16 + (n0 >> 6)) * 64;   // V^T rows for this col-panel are contiguous
#pragma unroll
    for (int sH = 0; sH < 8; sH++) {
      const int c = sH * 256 + t;
      const int ccol = c >> 4, k16 = c & 15;
      bf16x8 v = *(const bf16x8*)&T[ccol * TP + k16 * 8];
      *(bf16x8*)&dst[(size_t)(R0 + ccol) * 2048 + l0 + k16 * 8] = v;
    }
  }
}

// ---------------------------------------------------------------------------
// Output projection: ctx bf16 [4096][1024] @ Wo^T + bo -> fp32 out
// ---------------------------------------------------------------------------
__global__ __launch_bounds__(256, 3) void gemm_o(const __bf16* __restrict__ ctx, const __bf16* __restrict__ wto,
                                                 const float* __restrict__ bo, float* __restrict__ out) {
  __shared__ __align__(16) __bf16 smem[16384];

  const int flat = blockIdx.y * 8 + blockIdx.x;      // grid (8,32) = 256 blocks
  const int s = (flat & 7) * 32 + (flat >> 3);
  const int by = s >> 3, bx = s & 7;

  const int t = threadIdx.x;
  const int lane = t & 63;
  const int w = t >> 6;
  const int wm = w >> 1, wn = w & 1;
  const int l15 = lane & 15, quad = lane >> 4;
  const int m0 = by * 128, n0 = bx * 128;

  floatx4 acc[4][4];
#pragma unroll
  for (int i = 0; i < 4; i++)
#pragma unroll
    for (int j = 0; j < 4; j++) acc[i][j] = (floatx4){0.f, 0.f, 0.f, 0.f};

  gemm_core(ctx, wto, smem, m0, n0, wm, wn, l15, quad, t, acc);

  float bvv[4];
#pragma unroll
  for (int j = 0; j < 4; j++) bvv[j] = bo[n0 + wn * 64 + j * 16 + l15];

#pragma unroll
  for (int i = 0; i < 4; i++) {
    const int rowb = m0 + wm * 64 + i * 16 + quad * 4;
#pragma unroll
    for (int j = 0; j < 4; j++) {
      const int col = n0 + wn * 64 + j * 16 + l15;
#pragma unroll
      for (int rr = 0; rr < 4; rr++)
        out[(size_t)(rowb + rr) * 1024 + col] = acc[i][j][rr] + bvv[j];
    }
  }
}

// ---------------------------------------------------------------------------
// Flash attention, causal. q,k in [bh][L][64]; vT in [bh][64][L] (all bf16).
// Q pre-scaled by 0.125*log2e; no max subtraction (|S2|<~9 bounded), row sums
// deferred -> k-tile order irrelevant (pure accumulation).
//
// R10: measured law (R6-R9): time = iteration-slots/CU x 0.70us (>=2 blocks
// co-resident; 1.45us solo), INDEPENDENT of per-iteration work (R8/R9 dual-q
// free), FETCH (12 vs 119 MB no effect), balance. The barrier iteration's
// fixed serial chain is the quantum. Only lever: FEWER ITERATIONS.
//   -> KBLK=128: each barrier iteration stages+consumes TWO 64-k tiles
//      (halves, per-half layout identical to R8 -> all indexing reused).
//      Iters/block 34 -> ~17; slots/CU 68 -> ~34.
//   Structure: R8's dual-q pairing (A=31-p long, B=p short; uniform work,
//   512 blocks = 2/CU for chain-interleaving). LDS 64 KB (2 halves x dbuf),
//   still 2 blocks/CU. Counted vmcnt: 8 steady / 4,0 at the odd tail.
// ---------------------------------------------------------------------------
__global__ __launch_bounds__(256, 2) void flash_attn(const __bf16* __restrict__ q, const __bf16* __restrict__ k,
                                                     const __bf16* __restrict__ vT, __bf16* __restrict__ ctx) {
  __shared__ __align__(16) __bf16 kbuf[2][2][4096];  // [buf][half]: K 64r x 64d, swizzled
  __shared__ __align__(16) __bf16 vbuf[2][2][4096];  // [buf][half]: V^T 64d x 64k, swizzled

  const int t = threadIdx.x;
  const int lane = t & 63;
  const int w = t >> 6;                 // wave 0..3
  const int l15 = lane & 15, quad = lane >> 4;
  const int bh = blockIdx.y;
  const int p = (blockIdx.x + blockIdx.y) & 15;    // pair index, diag-swizzled
  const int qtA = 31 - p;               // long q-tile (64 rows); also last k-tile
  const int qtB = p;                    // short q-tile

  const __bf16* qb = q + (size_t)bh * L * DH;
  const __bf16* kb_ = k + (size_t)bh * L * DH;
  const __bf16* vb = vT + (size_t)bh * DH * L;

  // staging map: thread t covers LDS chunks c0 = t, c1 = 256+t (16B each)
  // within one half. chunk c: row r = c>>3, swizzled col8 = ((c&7)^(r&7))*8
  const int c0 = t, c1 = 256 + t;
  const int kr0 = c0 >> 3, kd0 = ((c0 & 7) ^ (kr0 & 7)) * 8;
  const int kr1 = c1 >> 3, kd1 = ((c1 & 7) ^ (kr1 & 7)) * 8;

  const int qrA = qtA * 64 + w * 16 + l15;         // this lane's q row, tile A
  const int qrB = qtB * 64 + w * 16 + l15;         // and tile B
  const bf16x8 aqA0 = *(const bf16x8*)&qb[(size_t)qrA * 64 + quad * 8];
  const bf16x8 aqA1 = *(const bf16x8*)&qb[(size_t)qrA * 64 + 32 + quad * 8];
  const bf16x8 aqB0 = *(const bf16x8*)&qb[(size_t)qrB * 64 + quad * 8];
  const bf16x8 aqB1 = *(const bf16x8*)&qb[(size_t)qrB * 64 + 32 + quad * 8];

  floatx4 oA[4], oB[4];
#pragma unroll
  for (int nt = 0; nt < 4; nt++) {
    oA[nt] = (floatx4){0.f, 0.f, 0.f, 0.f};
    oB[nt] = (floatx4){0.f, 0.f, 0.f, 0.f};
  }
  float psA = 0.f, psB = 0.f;

  // stage one 64-k tile (ktile) into (buf, half): 4 gld16/thread
  auto STAGE = [&](int buf, int half, int ktile) {
    const int kt = ktile * 64;
    gld16(&kb_[(size_t)(kt + kr0) * 64 + kd0], &kbuf[buf][half][c0 * 8]);
    gld16(&kb_[(size_t)(kt + kr1) * 64 + kd1], &kbuf[buf][half][c1 * 8]);
    gld16(&vb[(size_t)kr0 * L + kt + kd0],     &vbuf[buf][half][c0 * 8]);
    gld16(&vb[(size_t)kr1 * L + kt + kd1],     &vbuf[buf][half][c1 * 8]);
  };

  // compute one 64-k tile (both q-sub-tiles) from (buf, half)
  auto COMPUTE = [&](int buf, int half, int ktile) {
    const int kt = ktile * 64;
    const bool diagA = (ktile == qtA);
    const bool doB   = (ktile <= qtB);
    const bool diagB = (ktile == qtB);
    const __bf16* kbh = kbuf[buf][half];
    const __bf16* vbh = vbuf[buf][half];

#pragma unroll
    for (int sp = 0; sp < 2; ++sp) {      // two 32-wide kpos windows
      bf16x8 kf0[2], kf1[2];
#pragma unroll
      for (int u = 0; u < 2; ++u) {
        const int kr = (2 * sp + u) * 16 + l15;
        kf0[u] = *(const bf16x8*)&kbh[(kr * 8 + (quad ^ (kr & 7))) * 8];
        kf1[u] = *(const bf16x8*)&kbh[(kr * 8 + ((quad + 4) ^ (kr & 7))) * 8];
      }

      bf16x8 paA;
#pragma unroll
      for (int u = 0; u < 2; ++u) {
        floatx4 zz = (floatx4){0.f, 0.f, 0.f, 0.f};
        zz = MFMA16(kf0[u], aqA0, zz);
        zz = MFMA16(kf1[u], aqA1, zz);
        if (diagA) {
          const int kgb = kt + (2 * sp + u) * 16 + quad * 4;
#pragma unroll
          for (int rr = 0; rr < 4; rr++)
            if (kgb + rr > qrA) zz[rr] = NEG_BIG;
        }
#pragma unroll
        for (int rr = 0; rr < 4; rr++) {
          const float pv = __builtin_amdgcn_exp2f(zz[rr]);
          psA += pv;
          paA[u * 4 + rr] = (__bf16)pv;
        }
      }

      bf16x8 paB;
      if (doB) {
#pragma unroll
        for (int u = 0; u < 2; ++u) {
          floatx4 zz = (floatx4){0.f, 0.f, 0.f, 0.f};
          zz = MFMA16(kf0[u], aqB0, zz);
          zz = MFMA16(kf1[u], aqB1, zz);
          if (diagB) {
            const int kgb = kt + (2 * sp + u) * 16 + quad * 4;
#pragma unroll
            for (int rr = 0; rr < 4; rr++)
              if (kgb + rr > qrB) zz[rr] = NEG_BIG;
          }
#pragma unroll
          for (int rr = 0; rr < 4; rr++) {
            const float pv = __builtin_amdgcn_exp2f(zz[rr]);
            psB += pv;
            paB[u * 4 + rr] = (__bf16)pv;
          }
        }
      }

#pragma unroll
      for (int nt = 0; nt < 4; nt++) {
        const int d = nt * 16 + l15;
        const int x0 = (sp * 4 + (quad >> 1)) ^ (d & 7);
        const int x1 = (sp * 4 + 2 + (quad >> 1)) ^ (d & 7);
        union { bf16x8 v8; bf16x4 v4[2]; } uv;
        uv.v4[0] = *(const bf16x4*)&vbh[(d * 8 + x0) * 8 + (quad & 1) * 4];
        uv.v4[1] = *(const bf16x4*)&vbh[(d * 8 + x1) * 8 + (quad & 1) * 4];
        oA[nt] = MFMA16(paA, uv.v8, oA[nt]);
        if (doB) oB[nt] = MFMA16(paB, uv.v8, oB[nt]);
      }
    }
  };

  const int ntiles = qtA + 1;           // 17..32 k-tiles
  // prologue: stage tiles 0,1 into buf 0 (ntiles >= 17, both always exist)
  STAGE(0, 0, 0);
  STAGE(0, 1, 1);

  int it2 = 0;
#pragma unroll 1
  for (int base = 0; base < ntiles; base += 2, ++it2) {
    const int cur = it2 & 1;
    const int remn = ntiles - base - 2;          // tiles left to stage after this iter

    // ---- stage next iteration's tiles; wait ONLY this iter's (counted T4) ----
    if (remn >= 2) {
      STAGE(cur ^ 1, 0, base + 2);
      STAGE(cur ^ 1, 1, base + 3);
      asm volatile("s_waitcnt vmcnt(8)" ::: "memory");   // this iter's 8 landed
    } else if (remn == 1) {
      STAGE(cur ^ 1, 0, base + 2);
      asm volatile("s_waitcnt vmcnt(4)" ::: "memory");
    } else {
      asm volatile("s_waitcnt vmcnt(0)" ::: "memory");
    }
    __builtin_amdgcn_s_barrier();                        // tiles base(,base+1) resident

    COMPUTE(cur, 0, base);
    if (base + 1 < ntiles) COMPUTE(cur, 1, base + 1);    // block-uniform

    asm volatile("s_waitcnt lgkmcnt(0)" ::: "memory");   // my LDS reads retired
    __builtin_amdgcn_sched_barrier(0);                   // rule 18
    __builtin_amdgcn_s_barrier();                        // buffer may be overwritten next iter
  }

  // ---- epilogues (A then B): row-sum reduce + normalized store ----
  const int b = bh >> 4, h = bh & 15;

  psA += __shfl_xor(psA, 16);
  psA += __shfl_xor(psA, 32);
  const float invA = 1.f / psA;
#pragma unroll
  for (int rr = 0; rr < 4; rr++) {
    const float inv = __shfl(invA, (lane & 48) + quad * 4 + rr);
    const int row = qtA * 64 + w * 16 + quad * 4 + rr;
#pragma unroll
    for (int nt = 0; nt < 4; nt++) {
      const int col = h * 64 + nt * 16 + l15;
      ctx[((size_t)b * L + row) * 1024 + col] = (__bf16)(oA[nt][rr] * inv);
    }
  }

  psB += __shfl_xor(psB, 16);
  psB += __shfl_xor(psB, 32);
  const float invB = 1.f / psB;
#pragma unroll
  for (int rr = 0; rr < 4; rr++) {
    const float inv = __shfl(invB, (lane & 48) + quad * 4 + rr);
    const int row = qtB * 64 + w * 16 + quad * 4 + rr;
#pragma unroll
    for (int nt = 0; nt < 4; nt++) {
      const int col = h * 64 + nt * 16 + l15;
      ctx[((size_t)b * L + row) * 1024 + col] = (__bf16)(oB[nt][rr] * inv);
    }
  }
}

// ---------------------------------------------------------------------------
extern "C" void kernel_launch(void* const* d_in, const int* in_sizes, int n_in,
                              void* d_out, int out_size, void* d_ws, size_t ws_size,
                              hipStream_t stream) {
  const float* x_q = (const float*)d_in[0];
  const float* x_k = (const float*)d_in[1];
  const float* x_v = (const float*)d_in[2];
  const float* Wq  = (const float*)d_in[3];
  const float* bq  = (const float*)d_in[4];
  const float* Wk  = (const float*)d_in[5];
  const float* bk  = (const float*)d_in[6];
  const float* Wv  = (const float*)d_in[7];
  const float* bv  = (const float*)d_in[8];
  const float* Wo  = (const float*)d_in[9];
  const float* bo  = (const float*)d_in[10];

  char* ws = (char*)d_ws;
  __bf16* xc  = (__bf16*)ws;                          // 3 x [4096][1024] bf16 (24 MB), dead after gemm_proj
  __bf16* wt  = (__bf16*)(ws + ((size_t)24 << 20));   // 4 x 1024x1024 bf16    (8 MB)
  __bf16* qkv = (__bf16*)(ws + ((size_t)32 << 20));   // q,k [bh][l][d]; vT [bh][d][l] (24 MB)
  __bf16* ctx = (__bf16*)ws;                          // [B,L,1024] (8 MB) — reuses xc region
  __bf16* qp  = qkv;
  __bf16* kp  = qkv + (size_t)BB * L * D;
  __bf16* vtp = qkv + (size_t)2 * BB * L * D;

  cvt_x<<<dim3(1024, 1, 3), 256, 0, stream>>>(x_q, x_k, x_v, xc);
  transpose_w<<<dim3(32, 32, 4), dim3(32, 8), 0, stream>>>(Wq, Wk, Wv, Wo, wt);
  gemm_proj<<<dim3(8, 32, 3), 256, 0, stream>>>(xc, wt, bq, bk, bv, qkv);
  flash_attn<<<dim3(16, 32), 256, 0, stream>>>(qp, kp, vtp, ctx);
  gemm_o<<<dim3(8, 32), 256, 0, stream>>>(ctx, wt + (size_t)3 * D * D, bo, (float*)d_out);
}

// Round 11
// 202.609 us; speedup vs baseline: 1.0539x; 1.0175x over previous
//
#include <hip/hip_runtime.h>
#include <hip/hip_bf16.h>

typedef __bf16 bf16x8 __attribute__((ext_vector_type(8)));
typedef __bf16 bf16x4 __attribute__((ext_vector_type(4)));
typedef float floatx4 __attribute__((ext_vector_type(4)));

#define MFMA16(a, b, c) __builtin_amdgcn_mfma_f32_16x16x32_bf16(a, b, c, 0, 0, 0)
#define AS1 __attribute__((address_space(1)))
#define AS3 __attribute__((address_space(3)))

constexpr int D = 1024;
constexpr int L = 2048;
constexpr int BB = 2;
constexpr int DH = 64;
constexpr float NEG_BIG = -1e30f;                 // exp2 -> 0, fast-math safe
constexpr float SCALE_LOG2E = 0.125f * 1.4426950408889634f;  // folded into Q projection

// async global->LDS, 16B per lane (dest = wave-uniform base + lane*16)
__device__ __forceinline__ void gld16(const __bf16* g, __bf16* l) {
  __builtin_amdgcn_global_load_lds((AS1 void*)g, (AS3 void*)l, 16, 0, 0);
}

// ---------------------------------------------------------------------------
// prep (merged cvt_x + transpose_w: one launch fewer, independent work)
// z<3: fp32 x slab z -> bf16 xc. z in 3..6: W[K][N] fp32 -> bf16 Wt[N][K].
// ---------------------------------------------------------------------------
__global__ __launch_bounds__(256) void prep(const float* __restrict__ xq, const float* __restrict__ xk,
                                            const float* __restrict__ xv,
                                            const float* __restrict__ w0, const float* __restrict__ w1,
                                            const float* __restrict__ w2, const float* __restrict__ w3,
                                            __bf16* __restrict__ xc, __bf16* __restrict__ wt) {
  const int z = blockIdx.z;
  const int t = threadIdx.x;
  if (z < 3) {
    const float* src = z == 0 ? xq : z == 1 ? xk : xv;
    __bf16* dst = xc + (size_t)z * BB * L * D;
    const int N = BB * L * D;
    const int stride = gridDim.x * 256 * 4;
    for (int i = (blockIdx.x * 256 + t) * 4; i < N; i += stride) {
      float4 f = *(const float4*)&src[i];
      bf16x4 b = {(__bf16)f.x, (__bf16)f.y, (__bf16)f.z, (__bf16)f.w};
      *(bf16x4*)&dst[i] = b;
    }
  } else {
    __shared__ __bf16 tile[32][33];
    const int mat = z - 3;
    const float* src = mat == 0 ? w0 : mat == 1 ? w1 : mat == 2 ? w2 : w3;
    __bf16* dst = wt + (size_t)mat * D * D;
    const int bx = (blockIdx.x & 31) * 32, by = (blockIdx.x >> 5) * 32;
    const int tx = t & 31, ty = t >> 5;   // (32, 8) in flat 256
#pragma unroll
    for (int i = 0; i < 32; i += 8)
      tile[ty + i][tx] = (__bf16)src[(size_t)(by + ty + i) * D + bx + tx];
    __syncthreads();
#pragma unroll
    for (int i = 0; i < 32; i += 8)
      dst[(size_t)(bx + ty + i) * D + by + tx] = tile[tx][ty + i];
  }
}

// ---------------------------------------------------------------------------
// GEMM main loop: T4 counted-vmcnt 2-phase pipeline (frozen from R5).
// 128x128 tile, BK=32, double-buffered LDS in sm[0..16383].
// LDS swizzle (both-sides, rule 21): 2-row-granular XOR, 2-way = free.
// ---------------------------------------------------------------------------
__device__ __forceinline__ void stage32(const __bf16* __restrict__ A, const __bf16* __restrict__ Bt,
                                        __bf16* sA, __bf16* sB, int m0, int n0, int kb,
                                        int r, int sc, int dst) {
  // thread t: r = t>>2 (0..63), sc = ((t&3) ^ ((r>>1)&3))*8, dst = t*8
  gld16(&A[(size_t)(m0 + r) * 1024 + kb + sc],       &sA[dst]);
  gld16(&A[(size_t)(m0 + 64 + r) * 1024 + kb + sc],  &sA[2048 + dst]);  // (64+r)>>1 &3 == (r>>1)&3
  gld16(&Bt[(size_t)(n0 + r) * 1024 + kb + sc],      &sB[dst]);
  gld16(&Bt[(size_t)(n0 + 64 + r) * 1024 + kb + sc], &sB[2048 + dst]);
}

__device__ __forceinline__ void gemm_core(const __bf16* __restrict__ A, const __bf16* __restrict__ Bt,
                                          __bf16* sm, int m0, int n0, int wm, int wn,
                                          int l15, int quad, int t, floatx4 (&acc)[4][4]) {
  const int r = t >> 2;                         // 0..63
  const int sc = ((t & 3) ^ ((r >> 1) & 3)) * 8;
  const int dst = t * 8;
  const int sw2 = (l15 >> 1) & 3;               // (row>>1)&3 for all frag rows

  // prologue: stage K-step 0 into buffer 0
  stage32(A, Bt, sm, sm + 8192, m0, n0, 0, r, sc, dst);

  int cur = 0;
  for (int kb = 0; kb < 1024; kb += 32) {
    if (kb + 32 < 1024) {
      stage32(A, Bt, sm + (cur ^ 1) * 4096, sm + 8192 + (cur ^ 1) * 4096, m0, n0, kb + 32, r, sc, dst);
      asm volatile("s_waitcnt vmcnt(4)" ::: "memory");   // tile kb landed; kb+32 stays in flight
    } else {
      asm volatile("s_waitcnt vmcnt(0)" ::: "memory");   // last tile
    }
    __builtin_amdgcn_s_barrier();                        // all waves: tile kb resident

    const __bf16* sAc = sm + cur * 4096;
    const __bf16* sBc = sm + 8192 + cur * 4096;
    bf16x8 af[4], bf_[4];
#pragma unroll
    for (int i = 0; i < 4; i++) {
      const int row = wm * 64 + i * 16 + l15;
      af[i] = *(const bf16x8*)&sAc[(row * 4 + (quad ^ sw2)) * 8];
    }
#pragma unroll
    for (int j = 0; j < 4; j++) {
      const int row = wn * 64 + j * 16 + l15;
      bf_[j] = *(const bf16x8*)&sBc[(row * 4 + (quad ^ sw2)) * 8];
    }
    asm volatile("s_waitcnt lgkmcnt(0)" ::: "memory");   // my reads retired
    __builtin_amdgcn_sched_barrier(0);                   // rule 18: no MFMA hoist
    __builtin_amdgcn_s_barrier();                        // all reads retired -> overwrite ok

#pragma unroll
    for (int i = 0; i < 4; i++)
#pragma unroll
      for (int j = 0; j < 4; j++)
        acc[i][j] = MFMA16(af[i], bf_[j], acc[i][j]);    // overlaps next stage issue

    cur ^= 1;
  }
}

// ---------------------------------------------------------------------------
// QKV projection. z=0: Q scaled, [bh][l][dh]. z=1: K, [bh][l][dh].
// z=2: V TRANSPOSED [bh][dh][L], with l K-PERMUTED within each 32-block
// (store pos (q<<3)|(hi<<2)|j for l-bits (hi<<4)|(q<<2)|j): makes flash's
// PV B-fragment 16B-contiguous -> one ds_read_b128 instead of two b64 (R11).
// XCD-swizzled (FETCH 101.5 -> 22.7 MB, R2). Epilogue: LDS-repack +
// coalesced 16B stores (R6 win).
// ---------------------------------------------------------------------------
__global__ __launch_bounds__(256, 3) void gemm_proj(const __bf16* __restrict__ xc, const __bf16* __restrict__ wt,
                                                    const float* __restrict__ bq, const float* __restrict__ bk,
                                                    const float* __restrict__ bv, __bf16* __restrict__ qkv) {
  __shared__ __align__(16) __bf16 smem[17408];  // K-loop: 16384; epilogue T: 128x136

  const int flat = (blockIdx.z * 32 + blockIdx.y) * 8 + blockIdx.x;
  const int s = (flat & 7) * 96 + (flat >> 3);
  const int z = s >> 8;           // s / 256
  const int rem = s & 255;
  const int by = rem >> 3, bx = rem & 7;

  const __bf16* A = xc + (size_t)z * BB * L * D;
  const __bf16* Bt = wt + (size_t)z * D * D;
  const float* bias = z == 0 ? bq : z == 1 ? bk : bv;
  __bf16* dst = qkv + (size_t)z * BB * L * D;

  const int t = threadIdx.x;
  const int lane = t & 63;
  const int w = t >> 6;
  const int wm = w >> 1, wn = w & 1;
  const int l15 = lane & 15, quad = lane >> 4;
  const int m0 = by * 128, n0 = bx * 128;

  floatx4 acc[4][4];
#pragma unroll
  for (int i = 0; i < 4; i++)
#pragma unroll
    for (int j = 0; j < 4; j++) acc[i][j] = (floatx4){0.f, 0.f, 0.f, 0.f};

  gemm_core(A, Bt, smem, m0, n0, wm, wn, l15, quad, t, acc);

  float bvv[4];
#pragma unroll
  for (int j = 0; j < 4; j++) bvv[j] = bias[n0 + wn * 64 + j * 16 + l15];

  // ---- phase 1: C-tile -> LDS (K-loop buffers dead after final barrier) ----
  constexpr int TP = 136;                       // pad: row stride 272 B spreads banks
  __bf16* T = smem;
  if (z < 2) {
#pragma unroll
    for (int i = 0; i < 4; i++) {
      const int mrowb = wm * 64 + i * 16 + quad * 4;
#pragma unroll
      for (int j = 0; j < 4; j++) {
        const int ccol = wn * 64 + j * 16 + l15;
#pragma unroll
        for (int rr = 0; rr < 4; rr++) {
          float val = acc[i][j][rr] + bvv[j];
          if (z == 0) val *= SCALE_LOG2E;
          T[(mrowb + rr) * TP + ccol] = (__bf16)val;
        }
      }
    }
  } else {
    // transposed + k-permuted: rows i*16+quad*4+rr go to permuted position
    // wm*64 + (i>>1)*32 + quad*8 + (i&1)*4 + rr  (4-block stays contiguous)
#pragma unroll
    for (int i = 0; i < 4; i++) {
      const int mrowp = wm * 64 + (i >> 1) * 32 + quad * 8 + (i & 1) * 4;
#pragma unroll
      for (int j = 0; j < 4; j++) {
        const int ccol = wn * 64 + j * 16 + l15;
        bf16x4 v4;
#pragma unroll
        for (int rr = 0; rr < 4; rr++) v4[rr] = (__bf16)(acc[i][j][rr] + bvv[j]);
        *(bf16x4*)&T[ccol * TP + mrowp] = v4;
      }
    }
  }
  __syncthreads();

  // ---- phase 2: coalesced 16B stores (2048 chunks, 8 per thread) ----
  const int b = m0 >> 11;                       // tile never crosses batch boundary
  const int l0 = m0 & 2047;
  if (z < 2) {
#pragma unroll
    for (int sH = 0; sH < 8; sH++) {
      const int c = sH * 256 + t;
      const int mrow = c >> 4, k16 = c & 15;
      const int h = (n0 >> 6) + (k16 >> 3);
      const int d0 = (k16 & 7) * 8;
      bf16x8 v = *(const bf16x8*)&T[mrow * TP + k16 * 8];
      *(bf16x8*)&dst[((size_t)(b * 16 + h) * 2048 + l0 + mrow) * 64 + d0] = v;
    }
  } else {
    const int R0 = (b * 16 + (n0 >> 6)) * 64;   // V^T rows for this col-panel are contiguous
#pragma unroll
    for (int sH = 0; sH < 8; sH++) {
      const int c = sH * 256 + t;
      const int ccol = c >> 4, k16 = c & 15;
      bf16x8 v = *(const bf16x8*)&T[ccol * TP + k16 * 8];
      *(bf16x8*)&dst[(size_t)(R0 + ccol) * 2048 + l0 + k16 * 8] = v;
    }
  }
}

// ---------------------------------------------------------------------------
// Output projection: ctx bf16 [4096][1024] @ Wo^T + bo -> fp32 out
// ---------------------------------------------------------------------------
__global__ __launch_bounds__(256, 3) void gemm_o(const __bf16* __restrict__ ctx, const __bf16* __restrict__ wto,
                                                 const float* __restrict__ bo, float* __restrict__ out) {
  __shared__ __align__(16) __bf16 smem[16384];

  const int flat = blockIdx.y * 8 + blockIdx.x;      // grid (8,32) = 256 blocks
  const int s = (flat & 7) * 32 + (flat >> 3);
  const int by = s >> 3, bx = s & 7;

  const int t = threadIdx.x;
  const int lane = t & 63;
  const int w = t >> 6;
  const int wm = w >> 1, wn = w & 1;
  const int l15 = lane & 15, quad = lane >> 4;
  const int m0 = by * 128, n0 = bx * 128;

  floatx4 acc[4][4];
#pragma unroll
  for (int i = 0; i < 4; i++)
#pragma unroll
    for (int j = 0; j < 4; j++) acc[i][j] = (floatx4){0.f, 0.f, 0.f, 0.f};

  gemm_core(ctx, wto, smem, m0, n0, wm, wn, l15, quad, t, acc);

  float bvv[4];
#pragma unroll
  for (int j = 0; j < 4; j++) bvv[j] = bo[n0 + wn * 64 + j * 16 + l15];

#pragma unroll
  for (int i = 0; i < 4; i++) {
    const int rowb = m0 + wm * 64 + i * 16 + quad * 4;
#pragma unroll
    for (int j = 0; j < 4; j++) {
      const int col = n0 + wn * 64 + j * 16 + l15;
#pragma unroll
      for (int rr = 0; rr < 4; rr++)
        out[(size_t)(rowb + rr) * 1024 + col] = acc[i][j][rr] + bvv[j];
    }
  }
}

// ---------------------------------------------------------------------------
// Flash attention, causal. q,k in [bh][L][64]; vT in [bh][64][L'] where L' is
// k-permuted within 32-blocks (producer-side, see gemm_proj). Q pre-scaled;
// no max subtraction; row sums deferred.
//
// R11: per-slot cost proven ~linear in instruction content (R6-R10). Content
// cut: V fragment = ONE ds_read_b128 (was 2x b64) thanks to the producer-side
// k-permute: B-frag slot e needs V[k=(e>>2)*16+quad*4+(e&3)] which now sits
// at stored pos quad*8+e -> 16B contiguous, chunk (sp*4+quad)^(d&7).
// Structure: R10 (KBLK=128 per barrier iter, dual-q pairing A=31-p / B=p,
// 512 blocks = 2/CU, counted vmcnt 8/4/0).
// ---------------------------------------------------------------------------
__global__ __launch_bounds__(256, 2) void flash_attn(const __bf16* __restrict__ q, const __bf16* __restrict__ k,
                                                     const __bf16* __restrict__ vT, __bf16* __restrict__ ctx) {
  __shared__ __align__(16) __bf16 kbuf[2][2][4096];  // [buf][half]: K 64r x 64d, swizzled
  __shared__ __align__(16) __bf16 vbuf[2][2][4096];  // [buf][half]: V^T 64d x 64k', swizzled

  const int t = threadIdx.x;
  const int lane = t & 63;
  const int w = t >> 6;                 // wave 0..3
  const int l15 = lane & 15, quad = lane >> 4;
  const int bh = blockIdx.y;
  const int p = (blockIdx.x + blockIdx.y) & 15;    // pair index, diag-swizzled
  const int qtA = 31 - p;               // long q-tile (64 rows); also last k-tile
  const int qtB = p;                    // short q-tile

  const __bf16* qb = q + (size_t)bh * L * DH;
  const __bf16* kb_ = k + (size_t)bh * L * DH;
  const __bf16* vb = vT + (size_t)bh * DH * L;

  // staging map: thread t covers LDS chunks c0 = t, c1 = 256+t (16B each)
  // within one half. chunk c: row r = c>>3, swizzled col8 = ((c&7)^(r&7))*8
  const int c0 = t, c1 = 256 + t;
  const int kr0 = c0 >> 3, kd0 = ((c0 & 7) ^ (kr0 & 7)) * 8;
  const int kr1 = c1 >> 3, kd1 = ((c1 & 7) ^ (kr1 & 7)) * 8;

  const int qrA = qtA * 64 + w * 16 + l15;         // this lane's q row, tile A
  const int qrB = qtB * 64 + w * 16 + l15;         // and tile B
  const bf16x8 aqA0 = *(const bf16x8*)&qb[(size_t)qrA * 64 + quad * 8];
  const bf16x8 aqA1 = *(const bf16x8*)&qb[(size_t)qrA * 64 + 32 + quad * 8];
  const bf16x8 aqB0 = *(const bf16x8*)&qb[(size_t)qrB * 64 + quad * 8];
  const bf16x8 aqB1 = *(const bf16x8*)&qb[(size_t)qrB * 64 + 32 + quad * 8];

  floatx4 oA[4], oB[4];
#pragma unroll
  for (int nt = 0; nt < 4; nt++) {
    oA[nt] = (floatx4){0.f, 0.f, 0.f, 0.f};
    oB[nt] = (floatx4){0.f, 0.f, 0.f, 0.f};
  }
  float psA = 0.f, psB = 0.f;

  // stage one 64-k tile (ktile) into (buf, half): 4 gld16/thread
  auto STAGE = [&](int buf, int half, int ktile) {
    const int kt = ktile * 64;
    gld16(&kb_[(size_t)(kt + kr0) * 64 + kd0], &kbuf[buf][half][c0 * 8]);
    gld16(&kb_[(size_t)(kt + kr1) * 64 + kd1], &kbuf[buf][half][c1 * 8]);
    gld16(&vb[(size_t)kr0 * L + kt + kd0],     &vbuf[buf][half][c0 * 8]);
    gld16(&vb[(size_t)kr1 * L + kt + kd1],     &vbuf[buf][half][c1 * 8]);
  };

  // compute one 64-k tile (both q-sub-tiles) from (buf, half)
  auto COMPUTE = [&](int buf, int half, int ktile) {
    const int kt = ktile * 64;
    const bool diagA = (ktile == qtA);
    const bool doB   = (ktile <= qtB);
    const bool diagB = (ktile == qtB);
    const __bf16* kbh = kbuf[buf][half];
    const __bf16* vbh = vbuf[buf][half];

#pragma unroll
    for (int sp = 0; sp < 2; ++sp) {      // two 32-wide kpos windows
      bf16x8 kf0[2], kf1[2];
#pragma unroll
      for (int u = 0; u < 2; ++u) {
        const int kr = (2 * sp + u) * 16 + l15;
        kf0[u] = *(const bf16x8*)&kbh[(kr * 8 + (quad ^ (kr & 7))) * 8];
        kf1[u] = *(const bf16x8*)&kbh[(kr * 8 + ((quad + 4) ^ (kr & 7))) * 8];
      }

      bf16x8 paA;
#pragma unroll
      for (int u = 0; u < 2; ++u) {
        floatx4 zz = (floatx4){0.f, 0.f, 0.f, 0.f};
        zz = MFMA16(kf0[u], aqA0, zz);
        zz = MFMA16(kf1[u], aqA1, zz);
        if (diagA) {
          const int kgb = kt + (2 * sp + u) * 16 + quad * 4;
#pragma unroll
          for (int rr = 0; rr < 4; rr++)
            if (kgb + rr > qrA) zz[rr] = NEG_BIG;
        }
#pragma unroll
        for (int rr = 0; rr < 4; rr++) {
          const float pv = __builtin_amdgcn_exp2f(zz[rr]);
          psA += pv;
          paA[u * 4 + rr] = (__bf16)pv;
        }
      }

      bf16x8 paB;
      if (doB) {
#pragma unroll
        for (int u = 0; u < 2; ++u) {
          floatx4 zz = (floatx4){0.f, 0.f, 0.f, 0.f};
          zz = MFMA16(kf0[u], aqB0, zz);
          zz = MFMA16(kf1[u], aqB1, zz);
          if (diagB) {
            const int kgb = kt + (2 * sp + u) * 16 + quad * 4;
#pragma unroll
            for (int rr = 0; rr < 4; rr++)
              if (kgb + rr > qrB) zz[rr] = NEG_BIG;
          }
#pragma unroll
          for (int rr = 0; rr < 4; rr++) {
            const float pv = __builtin_amdgcn_exp2f(zz[rr]);
            psB += pv;
            paB[u * 4 + rr] = (__bf16)pv;
          }
        }
      }

      // ---- PV: one b128 V-fragment per nt (k-permuted storage) ----
#pragma unroll
      for (int nt = 0; nt < 4; nt++) {
        const int d = nt * 16 + l15;
        const int x = (sp * 4 + quad) ^ (d & 7);
        const bf16x8 vv = *(const bf16x8*)&vbh[(d * 8 + x) * 8];
        oA[nt] = MFMA16(paA, vv, oA[nt]);
        if (doB) oB[nt] = MFMA16(paB, vv, oB[nt]);
      }
    }
  };

  const int ntiles = qtA + 1;           // 17..32 k-tiles
  // prologue: stage tiles 0,1 into buf 0 (ntiles >= 17, both always exist)
  STAGE(0, 0, 0);
  STAGE(0, 1, 1);

  int it2 = 0;
#pragma unroll 1
  for (int base = 0; base < ntiles; base += 2, ++it2) {
    const int cur = it2 & 1;
    const int remn = ntiles - base - 2;          // tiles left to stage after this iter

    // ---- stage next iteration's tiles; wait ONLY this iter's (counted T4) ----
    if (remn >= 2) {
      STAGE(cur ^ 1, 0, base + 2);
      STAGE(cur ^ 1, 1, base + 3);
      asm volatile("s_waitcnt vmcnt(8)" ::: "memory");   // this iter's 8 landed
    } else if (remn == 1) {
      STAGE(cur ^ 1, 0, base + 2);
      asm volatile("s_waitcnt vmcnt(4)" ::: "memory");
    } else {
      asm volatile("s_waitcnt vmcnt(0)" ::: "memory");
    }
    __builtin_amdgcn_s_barrier();                        // tiles base(,base+1) resident

    COMPUTE(cur, 0, base);
    if (base + 1 < ntiles) COMPUTE(cur, 1, base + 1);    // block-uniform

    asm volatile("s_waitcnt lgkmcnt(0)" ::: "memory");   // my LDS reads retired
    __builtin_amdgcn_sched_barrier(0);                   // rule 18
    __builtin_amdgcn_s_barrier();                        // buffer may be overwritten next iter
  }

  // ---- epilogues (A then B): row-sum reduce + normalized store ----
  const int b = bh >> 4, h = bh & 15;

  psA += __shfl_xor(psA, 16);
  psA += __shfl_xor(psA, 32);
  const float invA = 1.f / psA;
#pragma unroll
  for (int rr = 0; rr < 4; rr++) {
    const float inv = __shfl(invA, (lane & 48) + quad * 4 + rr);
    const int row = qtA * 64 + w * 16 + quad * 4 + rr;
#pragma unroll
    for (int nt = 0; nt < 4; nt++) {
      const int col = h * 64 + nt * 16 + l15;
      ctx[((size_t)b * L + row) * 1024 + col] = (__bf16)(oA[nt][rr] * inv);
    }
  }

  psB += __shfl_xor(psB, 16);
  psB += __shfl_xor(psB, 32);
  const float invB = 1.f / psB;
#pragma unroll
  for (int rr = 0; rr < 4; rr++) {
    const float inv = __shfl(invB, (lane & 48) + quad * 4 + rr);
    const int row = qtB * 64 + w * 16 + quad * 4 + rr;
#pragma unroll
    for (int nt = 0; nt < 4; nt++) {
      const int col = h * 64 + nt * 16 + l15;
      ctx[((size_t)b * L + row) * 1024 + col] = (__bf16)(oB[nt][rr] * inv);
    }
  }
}

// ---------------------------------------------------------------------------
extern "C" void kernel_launch(void* const* d_in, const int* in_sizes, int n_in,
                              void* d_out, int out_size, void* d_ws, size_t ws_size,
                              hipStream_t stream) {
  const float* x_q = (const float*)d_in[0];
  const float* x_k = (const float*)d_in[1];
  const float* x_v = (const float*)d_in[2];
  const float* Wq  = (const float*)d_in[3];
  const float* bq  = (const float*)d_in[4];
  const float* Wk  = (const float*)d_in[5];
  const float* bk  = (const float*)d_in[6];
  const float* Wv  = (const float*)d_in[7];
  const float* bv  = (const float*)d_in[8];
  const float* Wo  = (const float*)d_in[9];
  const float* bo  = (const float*)d_in[10];

  char* ws = (char*)d_ws;
  __bf16* xc  = (__bf16*)ws;                          // 3 x [4096][1024] bf16 (24 MB), dead after gemm_proj
  __bf16* wt  = (__bf16*)(ws + ((size_t)24 << 20));   // 4 x 1024x1024 bf16    (8 MB)
  __bf16* qkv = (__bf16*)(ws + ((size_t)32 << 20));   // q,k [bh][l][d]; vT [bh][d][l'] (24 MB)
  __bf16* ctx = (__bf16*)ws;                          // [B,L,1024] (8 MB) — reuses xc region
  __bf16* qp  = qkv;
  __bf16* kp  = qkv + (size_t)BB * L * D;
  __bf16* vtp = qkv + (size_t)2 * BB * L * D;

  prep<<<dim3(1024, 1, 7), 256, 0, stream>>>(x_q, x_k, x_v, Wq, Wk, Wv, Wo, xc, wt);
  gemm_proj<<<dim3(8, 32, 3), 256, 0, stream>>>(xc, wt, bq, bk, bv, qkv);
  flash_attn<<<dim3(16, 32), 256, 0, stream>>>(qp, kp, vtp, ctx);
  gemm_o<<<dim3(8, 32), 256, 0, stream>>>(ctx, wt + (size_t)3 * D * D, bo, (float*)d_out);
}